// Round 6
// baseline (268.785 us; speedup 1.0000x reference)
//
#include <hip/hip_runtime.h>

// GCN policy net: 2× GCNConv(H=16) + global max pool + linear head.
// Build: fixed-capacity coarse buckets (256 dst/bucket, CAP edges each) ->
// k_bin tile-local LDS reorder with coalesced copy-out -> k_escan exact CSR
// bases -> k_sort per-bucket counting sort to node-ordered CSR + dis.
// Aggregate: feature-split (two 3.2MB half arrays, each < 4MB per-XCD L2) ->
// two gather passes per layer, wave per node, 32 edge-slots x 2 lanes.

#define FIN 128
#define HDIM 16
#define AOUT 10
#define NPB 256      // nodes per bucket (bucket = dst >> 8)
#define KMAX 512     // LDS sizing bound (padded): supports n <= 131072
#define TILE 4096    // edges per k_bin tile
#define CAP 9216     // fixed bucket capacity (expected 8192, sigma~90)

// init bucket cursors to arithmetic bases; off sentinel
__global__ void k_init(int* __restrict__ bcur, int* __restrict__ off,
                       int K, int n, int E) {
    int i = blockIdx.x * 256 + threadIdx.x;
    if (i < K) bcur[i] = i * CAP;
    if (i == 0) off[n] = E;
}

// tile-local reorder: histogram -> LDS scan -> bucket-sorted LDS buffer ->
// linear coalesced copy-out to per-bucket global windows.
__global__ __launch_bounds__(256) void k_bin(const int* __restrict__ src,
                                             const int* __restrict__ dst, int E,
                                             int* __restrict__ bcur,
                                             unsigned int* __restrict__ pairs, int K) {
    __shared__ int hist[KMAX], lofs[KMAX], run[KMAX], gbase[KMAX], ss[256];
    __shared__ unsigned int buf[TILE];
    __shared__ unsigned short bkt[TILE];
    int t = threadIdx.x;
    int e0 = blockIdx.x * TILE;
    int e1 = min(E, e0 + TILE);
    for (int i = t; i < KMAX; i += 256) hist[i] = 0;
    __syncthreads();
    // phase 1: tile histogram
    for (int e = e0 + t * 4; e < e1; e += 1024) {
        if (e + 4 <= e1) {
            int4 d4 = *reinterpret_cast<const int4*>(dst + e);
            atomicAdd(&hist[d4.x >> 8], 1);
            atomicAdd(&hist[d4.y >> 8], 1);
            atomicAdd(&hist[d4.z >> 8], 1);
            atomicAdd(&hist[d4.w >> 8], 1);
        } else {
            for (int q = e; q < e1; q++) atomicAdd(&hist[dst[q] >> 8], 1);
        }
    }
    __syncthreads();
    // phase 2: exclusive scan over padded 512 (2 entries per thread)
    int a0 = hist[2 * t], a1 = hist[2 * t + 1];
    int psum = a0 + a1;
    ss[t] = psum;
    for (int d = 1; d < 256; d <<= 1) {
        __syncthreads();
        int add = (t >= d) ? ss[t - d] : 0;
        __syncthreads();
        ss[t] += add;
    }
    __syncthreads();
    int excl = ss[t] - psum;
    lofs[2 * t] = excl;          run[2 * t] = excl;
    lofs[2 * t + 1] = excl + a0; run[2 * t + 1] = excl + a0;
    __syncthreads();
    // reserve global windows (one atomic per non-empty bucket)
    for (int b = t; b < K; b += 256)
        if (hist[b]) gbase[b] = atomicAdd(&bcur[b], hist[b]);
    __syncthreads();
    // phase 3: scatter into bucket-sorted LDS buffer
    for (int e = e0 + t * 4; e < e1; e += 1024) {
        if (e + 4 <= e1) {
            int4 d4 = *reinterpret_cast<const int4*>(dst + e);
            int4 s4 = *reinterpret_cast<const int4*>(src + e);
            int b, r;
            b = d4.x >> 8; r = atomicAdd(&run[b], 1);
            buf[r] = (unsigned)s4.x | ((unsigned)(d4.x & 255) << 17); bkt[r] = (unsigned short)b;
            b = d4.y >> 8; r = atomicAdd(&run[b], 1);
            buf[r] = (unsigned)s4.y | ((unsigned)(d4.y & 255) << 17); bkt[r] = (unsigned short)b;
            b = d4.z >> 8; r = atomicAdd(&run[b], 1);
            buf[r] = (unsigned)s4.z | ((unsigned)(d4.z & 255) << 17); bkt[r] = (unsigned short)b;
            b = d4.w >> 8; r = atomicAdd(&run[b], 1);
            buf[r] = (unsigned)s4.w | ((unsigned)(d4.w & 255) << 17); bkt[r] = (unsigned short)b;
        } else {
            for (int q = e; q < e1; q++) {
                int d = dst[q], s = src[q], b = d >> 8;
                int r = atomicAdd(&run[b], 1);
                buf[r] = (unsigned)s | ((unsigned)(d & 255) << 17);
                bkt[r] = (unsigned short)b;
            }
        }
    }
    __syncthreads();
    // phase 4: linear coalesced copy-out
    int m = e1 - e0;
    for (int i = t; i < m; i += 256) {
        int b = bkt[i];
        pairs[gbase[b] + i - lofs[b]] = buf[i];
    }
}

// exact per-bucket counts + exclusive scan -> compact CSR bases
__global__ __launch_bounds__(256) void k_escan(const int* __restrict__ bcur,
                                               int* __restrict__ cnt,
                                               int* __restrict__ ebase, int K) {
    __shared__ int sc[KMAX], ss[256];
    int t = threadIdx.x;
    for (int i = t; i < KMAX; i += 256) sc[i] = (i < K) ? (bcur[i] - i * CAP) : 0;
    __syncthreads();
    int a0 = sc[2 * t], a1 = sc[2 * t + 1];
    int psum = a0 + a1;
    ss[t] = psum;
    for (int d = 1; d < 256; d <<= 1) {
        __syncthreads();
        int add = (t >= d) ? ss[t - d] : 0;
        __syncthreads();
        ss[t] += add;
    }
    __syncthreads();
    int excl = ss[t] - psum;
    if (2 * t < K)     { cnt[2 * t] = a0;     ebase[2 * t] = excl; }
    if (2 * t + 1 < K) { cnt[2 * t + 1] = a1; ebase[2 * t + 1] = excl + a0; }
}

// per-bucket counting sort: pairs -> compact node-ordered srcidx + off + dis
__global__ __launch_bounds__(256) void k_sort(const unsigned int* __restrict__ pairs,
                                              const int* __restrict__ ebase,
                                              const int* __restrict__ cnt,
                                              int* __restrict__ srcidx,
                                              int* __restrict__ off,
                                              float* __restrict__ dis, int n) {
    __shared__ int lcnt[NPB], pre[NPB], cur[NPB];
    int b = blockIdx.x, t = threadIdx.x;
    lcnt[t] = 0;
    __syncthreads();
    int base = b * CAP, m = cnt[b], eb = ebase[b];
    for (int j = t; j < m; j += 256) atomicAdd(&lcnt[pairs[base + j] >> 17], 1);
    __syncthreads();
    int v = lcnt[t];
    pre[t] = v;
    for (int d = 1; d < 256; d <<= 1) {
        __syncthreads();
        int add = (t >= d) ? pre[t - d] : 0;
        __syncthreads();
        pre[t] += add;
    }
    __syncthreads();
    int excl = pre[t] - v;
    cur[t] = excl;
    int node = (b << 8) + t;
    if (node < n) {
        off[node] = eb + excl;
        dis[node] = rsqrtf((float)(v + 1));
    }
    __syncthreads();
    for (int j = t; j < m; j += 256) {
        unsigned p = pairs[base + j];
        int pos = eb + atomicAdd(&cur[p >> 17], 1);
        srcidx[pos] = (int)(p & 0x1FFFF);
    }
}

// gA[n][c]=dis*acc (c<8), gB[n][c-8] otherwise   (x: [n,128], W1: [128,16])
__global__ __launch_bounds__(256) void k_gemm1(const float* __restrict__ x,
                                               const float* __restrict__ W1,
                                               const float* __restrict__ dis,
                                               float* __restrict__ gA,
                                               float* __restrict__ gB, int n) {
    __shared__ float Ws[FIN * HDIM];
    for (int i = threadIdx.x; i < FIN * HDIM; i += 256) Ws[i] = W1[i];
    __syncthreads();
    int t = threadIdx.x;
    int node = blockIdx.x * 16 + (t >> 4);
    int c = t & 15;
    if (node >= n) return;
    const float* xr = x + (size_t)node * FIN;
    float acc = 0.f;
#pragma unroll
    for (int k = 0; k < FIN; k += 4) {
        float4 xv = *reinterpret_cast<const float4*>(xr + k);
        acc += xv.x * Ws[(k + 0) * HDIM + c];
        acc += xv.y * Ws[(k + 1) * HDIM + c];
        acc += xv.z * Ws[(k + 2) * HDIM + c];
        acc += xv.w * Ws[(k + 3) * HDIM + c];
    }
    float v = dis[node] * acc;
    if (c < 8) gA[(size_t)node * 8 + c] = v;
    else       gB[(size_t)node * 8 + (c - 8)] = v;
}

// half-feature aggregation: wave per node, 32 edge-slots x 2 lanes (float4
// piece of the 32B half-row). hH = relu(dis*(gH[n] + sum gH[src]) + biasH)
__global__ __launch_bounds__(256) void k_aggh(const float4* __restrict__ gH4,
                                              const int* __restrict__ off,
                                              const int* __restrict__ srcidx,
                                              const float* __restrict__ dis,
                                              const float4* __restrict__ bias4,
                                              float4* __restrict__ hH4, int n) {
    int t = threadIdx.x;
    int lane = t & 63;
    int node = blockIdx.x * 4 + (t >> 6);
    if (node >= n) return;
    int slot = lane >> 1, piece = lane & 1;
    int e0 = off[node], e1 = off[node + 1];
    float4 a = make_float4(0.f, 0.f, 0.f, 0.f);
    for (int e = e0 + slot; e < e1; e += 32) {
        int s = srcidx[e];
        float4 v = gH4[(size_t)s * 2 + piece];
        a.x += v.x; a.y += v.y; a.z += v.z; a.w += v.w;
    }
    if (slot == 0) {  // self-loop term
        float4 v = gH4[(size_t)node * 2 + piece];
        a.x += v.x; a.y += v.y; a.z += v.z; a.w += v.w;
    }
#pragma unroll
    for (int d = 2; d <= 32; d <<= 1) {
        a.x += __shfl_xor(a.x, d);
        a.y += __shfl_xor(a.y, d);
        a.z += __shfl_xor(a.z, d);
        a.w += __shfl_xor(a.w, d);
    }
    if (lane < 2) {  // piece == lane
        float dn = dis[node];
        float4 bb = bias4[lane];
        float4 o;
        o.x = fmaxf(dn * a.x + bb.x, 0.f);
        o.y = fmaxf(dn * a.y + bb.y, 0.f);
        o.z = fmaxf(dn * a.z + bb.z, 0.f);
        o.w = fmaxf(dn * a.w + bb.w, 0.f);
        hH4[(size_t)node * 2 + lane] = o;
    }
}

// g2 halves = dis[n] * (h[n] @ W2)   (W2: [16,16]; h in two half arrays)
__global__ __launch_bounds__(256) void k_gemm2(const float* __restrict__ hA,
                                               const float* __restrict__ hB,
                                               const float* __restrict__ W2,
                                               const float* __restrict__ dis,
                                               float* __restrict__ gA,
                                               float* __restrict__ gB, int n) {
    __shared__ float Ws[HDIM * HDIM];
    if (threadIdx.x < HDIM * HDIM) Ws[threadIdx.x] = W2[threadIdx.x];
    __syncthreads();
    int t = threadIdx.x;
    int node = blockIdx.x * 16 + (t >> 4);
    int c = t & 15;
    if (node >= n) return;
    const float* ha = hA + (size_t)node * 8;
    const float* hb = hB + (size_t)node * 8;
    float acc = 0.f;
#pragma unroll
    for (int j = 0; j < 8; j++) acc += ha[j] * Ws[j * HDIM + c];
#pragma unroll
    for (int j = 0; j < 8; j++) acc += hb[j] * Ws[(8 + j) * HDIM + c];
    float v = dis[node] * acc;
    if (c < 8) gA[(size_t)node * 8 + c] = v;
    else       gB[(size_t)node * 8 + (c - 8)] = v;
}

// global max pool over nodes (h >= 0 after relu, so uint atomicMax works)
__global__ __launch_bounds__(256) void k_maxpool(const float* __restrict__ hA,
                                                 const float* __restrict__ hB,
                                                 unsigned int* __restrict__ pooled, int n) {
    int t = threadIdx.x;
    int c = t & 15;
    int grp = t >> 4;  // 16 groups per block
    const float* src = (c < 8) ? hA : hB;
    int cc = c & 7;
    float m = 0.f;
    for (int node = blockIdx.x * 16 + grp; node < n; node += gridDim.x * 16)
        m = fmaxf(m, src[(size_t)node * 8 + cc]);
    __shared__ float s[256];
    s[t] = m;
    __syncthreads();
    for (int d = 128; d >= 16; d >>= 1) {
        if (t < d) s[t] = fmaxf(s[t], s[t + d]);
        __syncthreads();
    }
    if (t < 16) atomicMax(&pooled[t], __float_as_uint(s[t]));
}

// out[a] = sum_c pooled[c] * Wc[c][a] + bc[a]   (Wc: [16,10])
__global__ void k_final(const unsigned int* __restrict__ pooled, const float* __restrict__ Wc,
                        const float* __restrict__ bc, float* __restrict__ out) {
    __shared__ float p[HDIM];
    int t = threadIdx.x;
    if (t < HDIM) p[t] = __uint_as_float(pooled[t]);
    __syncthreads();
    if (t < AOUT) {
        float acc = bc[t];
#pragma unroll
        for (int c = 0; c < HDIM; c++) acc += p[c] * Wc[c * AOUT + t];
        out[t] = acc;
    }
}

extern "C" void kernel_launch(void* const* d_in, const int* in_sizes, int n_in,
                              void* d_out, int out_size, void* d_ws, size_t ws_size,
                              hipStream_t stream) {
    const float* x  = (const float*)d_in[0];
    const int*   ei = (const int*)d_in[1];
    const float* W1 = (const float*)d_in[2];
    const float* b1 = (const float*)d_in[3];
    const float* W2 = (const float*)d_in[4];
    const float* b2 = (const float*)d_in[5];
    const float* Wc = (const float*)d_in[6];
    const float* bc = (const float*)d_in[7];
    float* out = (float*)d_out;

    int n = in_sizes[0] / FIN;
    int E = in_sizes[1] / 2;
    const int* srcp = ei;       // edge_index[0]
    const int* dstp = ei + E;   // edge_index[1]
    int K = (n + NPB - 1) / NPB;   // 391 for n=100000

    char* ws = (char*)d_ws;
    auto alloc = [&](size_t bytes) -> char* {
        char* p = ws;
        ws += (bytes + 255) & ~(size_t)255;
        return p;
    };
    float*        dis   = (float*)alloc((size_t)n * 4);
    int*          cnt   = (int*)alloc((size_t)K * 4);
    int*          ebase = (int*)alloc((size_t)K * 4);
    int*          bcur  = (int*)alloc((size_t)K * 4);
    int*          off   = (int*)alloc((size_t)(n + 1) * 4);
    unsigned int* pairs = (unsigned int*)alloc((size_t)K * CAP * 4);
    int*          srcidx= (int*)alloc((size_t)E * 4);
    float*        gA    = (float*)alloc((size_t)n * 8 * 4);
    float*        gB    = (float*)alloc((size_t)n * 8 * 4);
    float*        hA    = (float*)alloc((size_t)n * 8 * 4);
    float*        hB    = (float*)alloc((size_t)n * 8 * 4);
    unsigned int* pooled= (unsigned int*)alloc(64);

    hipMemsetAsync(pooled, 0, 64, stream);

    k_init<<<(K + 255) / 256, 256, 0, stream>>>(bcur, off, K, n, E);
    k_bin<<<(E + TILE - 1) / TILE, 256, 0, stream>>>(srcp, dstp, E, bcur, pairs, K);
    k_escan<<<1, 256, 0, stream>>>(bcur, cnt, ebase, K);
    k_sort<<<K, 256, 0, stream>>>(pairs, ebase, cnt, srcidx, off, dis, n);

    k_gemm1<<<(n + 15) / 16, 256, 0, stream>>>(x, W1, dis, gA, gB, n);
    k_aggh<<<(n + 3) / 4, 256, 0, stream>>>((const float4*)gA, off, srcidx, dis,
                                            (const float4*)b1, (float4*)hA, n);
    k_aggh<<<(n + 3) / 4, 256, 0, stream>>>((const float4*)gB, off, srcidx, dis,
                                            (const float4*)(b1 + 8), (float4*)hB, n);
    k_gemm2<<<(n + 15) / 16, 256, 0, stream>>>(hA, hB, W2, dis, gA, gB, n);
    k_aggh<<<(n + 3) / 4, 256, 0, stream>>>((const float4*)gA, off, srcidx, dis,
                                            (const float4*)b2, (float4*)hA, n);
    k_aggh<<<(n + 3) / 4, 256, 0, stream>>>((const float4*)gB, off, srcidx, dis,
                                            (const float4*)(b2 + 8), (float4*)hB, n);

    k_maxpool<<<256, 256, 0, stream>>>(hA, hB, pooled, n);
    k_final<<<1, 64, 0, stream>>>(pooled, Wc, bc, out);
}

// Round 7
// 191.124 us; speedup vs baseline: 1.4063x; 1.4063x over previous
//
#include <hip/hip_runtime.h>
#include <hip/hip_fp16.h>

// GCN policy net: 2× GCNConv(H=16) + global max pool + linear head.
// Build: fixed-capacity coarse buckets -> k_bin tile-local LDS reorder ->
// k_escan -> k_sort (node-ordered CSR + dis).
// Compute: MFMA f16 gemms (x@W1, h@W2) with fused dis-scale + f16 pack;
// messages g16 = [n][16] fp16 (32B rows, 3.2MB -> L2-resident).
// Aggregate: 2 lanes per node (16B half-row each), thread-serial edge loop,
// packed f16 accumulate, no cross-lane reduce. Minimizes divergent
// lane-addresses (TA-rate bound per round-5 evidence).

#define FIN 128
#define HDIM 16
#define AOUT 10
#define NPB 256      // nodes per bucket (bucket = dst >> 8)
#define KMAX 512     // LDS sizing bound (padded): supports n <= 131072
#define TILE 4096    // edges per k_bin tile
#define CAP 9216     // fixed bucket capacity (expected 8192, sigma~90)

typedef _Float16 f16x8 __attribute__((ext_vector_type(8)));
typedef float f32x4 __attribute__((ext_vector_type(4)));

// init bucket cursors to arithmetic bases; off sentinel
__global__ void k_init(int* __restrict__ bcur, int* __restrict__ off,
                       int K, int n, int E) {
    int i = blockIdx.x * 256 + threadIdx.x;
    if (i < K) bcur[i] = i * CAP;
    if (i == 0) off[n] = E;
}

// tile-local reorder: histogram -> LDS scan -> bucket-sorted LDS buffer ->
// linear coalesced copy-out to per-bucket global windows.
__global__ __launch_bounds__(256) void k_bin(const int* __restrict__ src,
                                             const int* __restrict__ dst, int E,
                                             int* __restrict__ bcur,
                                             unsigned int* __restrict__ pairs, int K) {
    __shared__ int hist[KMAX], lofs[KMAX], run[KMAX], gbase[KMAX], ss[256];
    __shared__ unsigned int buf[TILE];
    __shared__ unsigned short bkt[TILE];
    int t = threadIdx.x;
    int e0 = blockIdx.x * TILE;
    int e1 = min(E, e0 + TILE);
    for (int i = t; i < KMAX; i += 256) hist[i] = 0;
    __syncthreads();
    // phase 1: tile histogram
    for (int e = e0 + t * 4; e < e1; e += 1024) {
        if (e + 4 <= e1) {
            int4 d4 = *reinterpret_cast<const int4*>(dst + e);
            atomicAdd(&hist[d4.x >> 8], 1);
            atomicAdd(&hist[d4.y >> 8], 1);
            atomicAdd(&hist[d4.z >> 8], 1);
            atomicAdd(&hist[d4.w >> 8], 1);
        } else {
            for (int q = e; q < e1; q++) atomicAdd(&hist[dst[q] >> 8], 1);
        }
    }
    __syncthreads();
    // phase 2: exclusive scan over padded 512 (2 entries per thread)
    int a0 = hist[2 * t], a1 = hist[2 * t + 1];
    int psum = a0 + a1;
    ss[t] = psum;
    for (int d = 1; d < 256; d <<= 1) {
        __syncthreads();
        int add = (t >= d) ? ss[t - d] : 0;
        __syncthreads();
        ss[t] += add;
    }
    __syncthreads();
    int excl = ss[t] - psum;
    lofs[2 * t] = excl;          run[2 * t] = excl;
    lofs[2 * t + 1] = excl + a0; run[2 * t + 1] = excl + a0;
    __syncthreads();
    // reserve global windows (one atomic per non-empty bucket)
    for (int b = t; b < K; b += 256)
        if (hist[b]) gbase[b] = atomicAdd(&bcur[b], hist[b]);
    __syncthreads();
    // phase 3: scatter into bucket-sorted LDS buffer
    for (int e = e0 + t * 4; e < e1; e += 1024) {
        if (e + 4 <= e1) {
            int4 d4 = *reinterpret_cast<const int4*>(dst + e);
            int4 s4 = *reinterpret_cast<const int4*>(src + e);
            int b, r;
            b = d4.x >> 8; r = atomicAdd(&run[b], 1);
            buf[r] = (unsigned)s4.x | ((unsigned)(d4.x & 255) << 17); bkt[r] = (unsigned short)b;
            b = d4.y >> 8; r = atomicAdd(&run[b], 1);
            buf[r] = (unsigned)s4.y | ((unsigned)(d4.y & 255) << 17); bkt[r] = (unsigned short)b;
            b = d4.z >> 8; r = atomicAdd(&run[b], 1);
            buf[r] = (unsigned)s4.z | ((unsigned)(d4.z & 255) << 17); bkt[r] = (unsigned short)b;
            b = d4.w >> 8; r = atomicAdd(&run[b], 1);
            buf[r] = (unsigned)s4.w | ((unsigned)(d4.w & 255) << 17); bkt[r] = (unsigned short)b;
        } else {
            for (int q = e; q < e1; q++) {
                int d = dst[q], s = src[q], b = d >> 8;
                int r = atomicAdd(&run[b], 1);
                buf[r] = (unsigned)s | ((unsigned)(d & 255) << 17);
                bkt[r] = (unsigned short)b;
            }
        }
    }
    __syncthreads();
    // phase 4: linear coalesced copy-out
    int m = e1 - e0;
    for (int i = t; i < m; i += 256) {
        int b = bkt[i];
        pairs[gbase[b] + i - lofs[b]] = buf[i];
    }
}

// exact per-bucket counts + exclusive scan -> compact CSR bases
__global__ __launch_bounds__(256) void k_escan(const int* __restrict__ bcur,
                                               int* __restrict__ cnt,
                                               int* __restrict__ ebase, int K) {
    __shared__ int sc[KMAX], ss[256];
    int t = threadIdx.x;
    for (int i = t; i < KMAX; i += 256) sc[i] = (i < K) ? (bcur[i] - i * CAP) : 0;
    __syncthreads();
    int a0 = sc[2 * t], a1 = sc[2 * t + 1];
    int psum = a0 + a1;
    ss[t] = psum;
    for (int d = 1; d < 256; d <<= 1) {
        __syncthreads();
        int add = (t >= d) ? ss[t - d] : 0;
        __syncthreads();
        ss[t] += add;
    }
    __syncthreads();
    int excl = ss[t] - psum;
    if (2 * t < K)     { cnt[2 * t] = a0;     ebase[2 * t] = excl; }
    if (2 * t + 1 < K) { cnt[2 * t + 1] = a1; ebase[2 * t + 1] = excl + a0; }
}

// per-bucket counting sort: pairs -> compact node-ordered srcidx + off + dis
__global__ __launch_bounds__(256) void k_sort(const unsigned int* __restrict__ pairs,
                                              const int* __restrict__ ebase,
                                              const int* __restrict__ cnt,
                                              int* __restrict__ srcidx,
                                              int* __restrict__ off,
                                              float* __restrict__ dis, int n) {
    __shared__ int lcnt[NPB], pre[NPB], cur[NPB];
    int b = blockIdx.x, t = threadIdx.x;
    lcnt[t] = 0;
    __syncthreads();
    int base = b * CAP, m = cnt[b], eb = ebase[b];
    for (int j = t; j < m; j += 256) atomicAdd(&lcnt[pairs[base + j] >> 17], 1);
    __syncthreads();
    int v = lcnt[t];
    pre[t] = v;
    for (int d = 1; d < 256; d <<= 1) {
        __syncthreads();
        int add = (t >= d) ? pre[t - d] : 0;
        __syncthreads();
        pre[t] += add;
    }
    __syncthreads();
    int excl = pre[t] - v;
    cur[t] = excl;
    int node = (b << 8) + t;
    if (node < n) {
        off[node] = eb + excl;
        dis[node] = rsqrtf((float)(v + 1));
    }
    __syncthreads();
    for (int j = t; j < m; j += 256) {
        unsigned p = pairs[base + j];
        int pos = eb + atomicAdd(&cur[p >> 17], 1);
        srcidx[pos] = (int)(p & 0x1FFFF);
    }
}

// MFMA gemm1: g16[nd][c] = f16(dis[nd] * (x @ W1)[nd][c]).
// A: lane holds x[node0 + (l&15)][kc*32 + (l>>4)*8 + j]; B: W1 col (l&15).
// C: col = l&15, row = (l>>4)*4 + i (verified gfx950 mapping).
__global__ __launch_bounds__(256) void k_gemm1(const float* __restrict__ x,
                                               const float* __restrict__ W1,
                                               const float* __restrict__ dis,
                                               __half* __restrict__ g16, int n) {
    int l = threadIdx.x & 63;
    int cc = l & 15, kg = l >> 4;
    f16x8 bfrag[4];
#pragma unroll
    for (int kc = 0; kc < 4; kc++)
#pragma unroll
        for (int j = 0; j < 8; j++)
            bfrag[kc][j] = (_Float16)W1[(kc * 32 + kg * 8 + j) * HDIM + cc];
    int tile = blockIdx.x * 4 + (threadIdx.x >> 6);
    int node0 = tile * 16;
    if (node0 >= n) return;
    const float* xr = x + (size_t)(node0 + cc) * FIN;
    f32x4 acc = {0.f, 0.f, 0.f, 0.f};
#pragma unroll
    for (int kc = 0; kc < 4; kc++) {
        float4 xa = *reinterpret_cast<const float4*>(xr + kc * 32 + kg * 8);
        float4 xb = *reinterpret_cast<const float4*>(xr + kc * 32 + kg * 8 + 4);
        f16x8 a;
        a[0] = (_Float16)xa.x; a[1] = (_Float16)xa.y;
        a[2] = (_Float16)xa.z; a[3] = (_Float16)xa.w;
        a[4] = (_Float16)xb.x; a[5] = (_Float16)xb.y;
        a[6] = (_Float16)xb.z; a[7] = (_Float16)xb.w;
        acc = __builtin_amdgcn_mfma_f32_16x16x32_f16(a, bfrag[kc], acc, 0, 0, 0);
    }
#pragma unroll
    for (int i = 0; i < 4; i++) {
        int nd = node0 + kg * 4 + i;
        g16[(size_t)nd * HDIM + cc] = (__half)(dis[nd] * acc[i]);
    }
}

// MFMA gemm2: g16 = f16(dis * (h @ W2)), K=16 zero-padded to 32.
__global__ __launch_bounds__(256) void k_gemm2(const float* __restrict__ h,
                                               const float* __restrict__ W2,
                                               const float* __restrict__ dis,
                                               __half* __restrict__ g16, int n) {
    int l = threadIdx.x & 63;
    int cc = l & 15, kg = l >> 4;
    f16x8 bfrag = {0, 0, 0, 0, 0, 0, 0, 0};
    if (kg < 2) {
#pragma unroll
        for (int j = 0; j < 8; j++)
            bfrag[j] = (_Float16)W2[(kg * 8 + j) * HDIM + cc];
    }
    int tile = blockIdx.x * 4 + (threadIdx.x >> 6);
    int node0 = tile * 16;
    if (node0 >= n) return;
    f16x8 a = {0, 0, 0, 0, 0, 0, 0, 0};
    if (kg < 2) {
        const float* hr = h + (size_t)(node0 + cc) * HDIM + kg * 8;
        float4 xa = *reinterpret_cast<const float4*>(hr);
        float4 xb = *reinterpret_cast<const float4*>(hr + 4);
        a[0] = (_Float16)xa.x; a[1] = (_Float16)xa.y;
        a[2] = (_Float16)xa.z; a[3] = (_Float16)xa.w;
        a[4] = (_Float16)xb.x; a[5] = (_Float16)xb.y;
        a[6] = (_Float16)xb.z; a[7] = (_Float16)xb.w;
    }
    f32x4 acc = {0.f, 0.f, 0.f, 0.f};
    acc = __builtin_amdgcn_mfma_f32_16x16x32_f16(a, bfrag, acc, 0, 0, 0);
#pragma unroll
    for (int i = 0; i < 4; i++) {
        int nd = node0 + kg * 4 + i;
        g16[(size_t)nd * HDIM + cc] = (__half)(dis[nd] * acc[i]);
    }
}

// aggregation: 2 lanes per node, piece = 16B half of the 32B fp16 row.
// Thread-serial edge loop, packed f16 accumulate, no cross-lane reduce.
// h[n] = relu(dis[n] * (g16[n] + sum g16[src]) + bias)
__global__ __launch_bounds__(256) void k_agg16(const __half* __restrict__ g16,
                                               const int* __restrict__ off,
                                               const int* __restrict__ srcidx,
                                               const float* __restrict__ dis,
                                               const float* __restrict__ bias,
                                               float* __restrict__ h, int n) {
    int tid = blockIdx.x * 256 + threadIdx.x;
    int node = tid >> 1, piece = tid & 1;
    if (node >= n) return;
    const uint4* gp = reinterpret_cast<const uint4*>(g16);
    int e0 = off[node], e1 = off[node + 1];
    uint4 v = gp[(size_t)node * 2 + piece];   // self-loop term
    __half2 a0 = __builtin_bit_cast(__half2, v.x);
    __half2 a1 = __builtin_bit_cast(__half2, v.y);
    __half2 a2 = __builtin_bit_cast(__half2, v.z);
    __half2 a3 = __builtin_bit_cast(__half2, v.w);
    for (int e = e0; e < e1; e++) {
        uint4 w = gp[(size_t)srcidx[e] * 2 + piece];
        a0 = __hadd2(a0, __builtin_bit_cast(__half2, w.x));
        a1 = __hadd2(a1, __builtin_bit_cast(__half2, w.y));
        a2 = __hadd2(a2, __builtin_bit_cast(__half2, w.z));
        a3 = __hadd2(a3, __builtin_bit_cast(__half2, w.w));
    }
    float dn = dis[node];
    const float* bp = bias + piece * 8;
    float2 f0 = __half22float2(a0), f1 = __half22float2(a1);
    float2 f2 = __half22float2(a2), f3 = __half22float2(a3);
    float4 o0, o1;
    o0.x = fmaxf(dn * f0.x + bp[0], 0.f); o0.y = fmaxf(dn * f0.y + bp[1], 0.f);
    o0.z = fmaxf(dn * f1.x + bp[2], 0.f); o0.w = fmaxf(dn * f1.y + bp[3], 0.f);
    o1.x = fmaxf(dn * f2.x + bp[4], 0.f); o1.y = fmaxf(dn * f2.y + bp[5], 0.f);
    o1.z = fmaxf(dn * f3.x + bp[6], 0.f); o1.w = fmaxf(dn * f3.y + bp[7], 0.f);
    float4* hp = reinterpret_cast<float4*>(h + (size_t)node * HDIM + piece * 8);
    hp[0] = o0; hp[1] = o1;
}

// global max pool over nodes (h >= 0 after relu, so uint atomicMax works)
__global__ __launch_bounds__(256) void k_maxpool(const float* __restrict__ h,
                                                 unsigned int* __restrict__ pooled, int n) {
    int t = threadIdx.x;
    int c = t & 15;
    int grp = t >> 4;  // 16 groups per block
    float m = 0.f;
    for (int node = blockIdx.x * 16 + grp; node < n; node += gridDim.x * 16)
        m = fmaxf(m, h[(size_t)node * HDIM + c]);
    __shared__ float s[256];
    s[t] = m;
    __syncthreads();
    for (int d = 128; d >= 16; d >>= 1) {
        if (t < d) s[t] = fmaxf(s[t], s[t + d]);
        __syncthreads();
    }
    if (t < 16) atomicMax(&pooled[t], __float_as_uint(s[t]));
}

// out[a] = sum_c pooled[c] * Wc[c][a] + bc[a]   (Wc: [16,10])
__global__ void k_final(const unsigned int* __restrict__ pooled, const float* __restrict__ Wc,
                        const float* __restrict__ bc, float* __restrict__ out) {
    __shared__ float p[HDIM];
    int t = threadIdx.x;
    if (t < HDIM) p[t] = __uint_as_float(pooled[t]);
    __syncthreads();
    if (t < AOUT) {
        float acc = bc[t];
#pragma unroll
        for (int c = 0; c < HDIM; c++) acc += p[c] * Wc[c * AOUT + t];
        out[t] = acc;
    }
}

extern "C" void kernel_launch(void* const* d_in, const int* in_sizes, int n_in,
                              void* d_out, int out_size, void* d_ws, size_t ws_size,
                              hipStream_t stream) {
    const float* x  = (const float*)d_in[0];
    const int*   ei = (const int*)d_in[1];
    const float* W1 = (const float*)d_in[2];
    const float* b1 = (const float*)d_in[3];
    const float* W2 = (const float*)d_in[4];
    const float* b2 = (const float*)d_in[5];
    const float* Wc = (const float*)d_in[6];
    const float* bc = (const float*)d_in[7];
    float* out = (float*)d_out;

    int n = in_sizes[0] / FIN;
    int E = in_sizes[1] / 2;
    const int* srcp = ei;       // edge_index[0]
    const int* dstp = ei + E;   // edge_index[1]
    int K = (n + NPB - 1) / NPB;   // 391 for n=100000

    char* ws = (char*)d_ws;
    auto alloc = [&](size_t bytes) -> char* {
        char* p = ws;
        ws += (bytes + 255) & ~(size_t)255;
        return p;
    };
    float*        dis   = (float*)alloc((size_t)n * 4);
    int*          cnt   = (int*)alloc((size_t)K * 4);
    int*          ebase = (int*)alloc((size_t)K * 4);
    int*          bcur  = (int*)alloc((size_t)K * 4);
    int*          off   = (int*)alloc((size_t)(n + 1) * 4);
    unsigned int* pairs = (unsigned int*)alloc((size_t)K * CAP * 4);
    int*          srcidx= (int*)alloc((size_t)E * 4);
    __half*       g16   = (__half*)alloc((size_t)n * HDIM * 2);
    float*        h     = (float*)alloc((size_t)n * HDIM * 4);
    unsigned int* pooled= (unsigned int*)alloc(64);

    hipMemsetAsync(pooled, 0, 64, stream);

    k_init<<<(K + 255) / 256, 256, 0, stream>>>(bcur, off, K, n, E);
    k_bin<<<(E + TILE - 1) / TILE, 256, 0, stream>>>(srcp, dstp, E, bcur, pairs, K);
    k_escan<<<1, 256, 0, stream>>>(bcur, cnt, ebase, K);
    k_sort<<<K, 256, 0, stream>>>(pairs, ebase, cnt, srcidx, off, dis, n);

    int ntile = (n + 15) / 16;
    int gblocks = (ntile + 3) / 4;
    k_gemm1<<<gblocks, 256, 0, stream>>>(x, W1, dis, g16, n);
    k_agg16<<<(2 * n + 255) / 256, 256, 0, stream>>>(g16, off, srcidx, dis, b1, h, n);
    k_gemm2<<<gblocks, 256, 0, stream>>>(h, W2, dis, g16, n);
    k_agg16<<<(2 * n + 255) / 256, 256, 0, stream>>>(g16, off, srcidx, dis, b2, h, n);

    k_maxpool<<<256, 256, 0, stream>>>(h, pooled, n);
    k_final<<<1, 64, 0, stream>>>(pooled, Wc, bc, out);
}

// Round 8
// 153.900 us; speedup vs baseline: 1.7465x; 1.2419x over previous
//
#include <hip/hip_runtime.h>
#include <hip/hip_fp16.h>

// GCN policy net: 2× GCNConv(H=16) + global max pool + linear head.
// Build: fixed-capacity coarse buckets -> k_bin tile-local LDS reorder ->
// k_escan -> k_sort (node-ordered CSR + dis).
// Compute: MFMA f16 gemms (x@W1, h@W2) with fused dis-scale + f16 pack;
// messages g16 = [n][16] fp16 (32B rows, 3.2MB -> L2-resident).
// Aggregate: 4 threads per node (piece x edge-half), 4-wide unrolled gather
// loop (4 independent 16B gathers in flight/thread), halves combined with
// one shfl_xor. Raises occupancy 22%->~75% and per-thread MLP (round-6
// evidence: latency-bound at 22% occupancy, VALUBusy 4%).

#define FIN 128
#define HDIM 16
#define AOUT 10
#define NPB 256      // nodes per bucket (bucket = dst >> 8)
#define KMAX 512     // LDS sizing bound (padded): supports n <= 131072
#define TILE 4096    // edges per k_bin tile
#define CAP 9216     // fixed bucket capacity (expected 8192, sigma~90)

typedef _Float16 f16x8 __attribute__((ext_vector_type(8)));
typedef float f32x4 __attribute__((ext_vector_type(4)));

// init bucket cursors to arithmetic bases; off sentinel
__global__ void k_init(int* __restrict__ bcur, int* __restrict__ off,
                       int K, int n, int E) {
    int i = blockIdx.x * 256 + threadIdx.x;
    if (i < K) bcur[i] = i * CAP;
    if (i == 0) off[n] = E;
}

// tile-local reorder: histogram -> LDS scan -> bucket-sorted LDS buffer ->
// linear coalesced copy-out to per-bucket global windows.
__global__ __launch_bounds__(256) void k_bin(const int* __restrict__ src,
                                             const int* __restrict__ dst, int E,
                                             int* __restrict__ bcur,
                                             unsigned int* __restrict__ pairs, int K) {
    __shared__ int hist[KMAX], lofs[KMAX], run[KMAX], gbase[KMAX], ss[256];
    __shared__ unsigned int buf[TILE];
    __shared__ unsigned short bkt[TILE];
    int t = threadIdx.x;
    int e0 = blockIdx.x * TILE;
    int e1 = min(E, e0 + TILE);
    for (int i = t; i < KMAX; i += 256) hist[i] = 0;
    __syncthreads();
    // phase 1: tile histogram
    for (int e = e0 + t * 4; e < e1; e += 1024) {
        if (e + 4 <= e1) {
            int4 d4 = *reinterpret_cast<const int4*>(dst + e);
            atomicAdd(&hist[d4.x >> 8], 1);
            atomicAdd(&hist[d4.y >> 8], 1);
            atomicAdd(&hist[d4.z >> 8], 1);
            atomicAdd(&hist[d4.w >> 8], 1);
        } else {
            for (int q = e; q < e1; q++) atomicAdd(&hist[dst[q] >> 8], 1);
        }
    }
    __syncthreads();
    // phase 2: exclusive scan over padded 512 (2 entries per thread)
    int a0 = hist[2 * t], a1 = hist[2 * t + 1];
    int psum = a0 + a1;
    ss[t] = psum;
    for (int d = 1; d < 256; d <<= 1) {
        __syncthreads();
        int add = (t >= d) ? ss[t - d] : 0;
        __syncthreads();
        ss[t] += add;
    }
    __syncthreads();
    int excl = ss[t] - psum;
    lofs[2 * t] = excl;          run[2 * t] = excl;
    lofs[2 * t + 1] = excl + a0; run[2 * t + 1] = excl + a0;
    __syncthreads();
    // reserve global windows (one atomic per non-empty bucket)
    for (int b = t; b < K; b += 256)
        if (hist[b]) gbase[b] = atomicAdd(&bcur[b], hist[b]);
    __syncthreads();
    // phase 3: scatter into bucket-sorted LDS buffer
    for (int e = e0 + t * 4; e < e1; e += 1024) {
        if (e + 4 <= e1) {
            int4 d4 = *reinterpret_cast<const int4*>(dst + e);
            int4 s4 = *reinterpret_cast<const int4*>(src + e);
            int b, r;
            b = d4.x >> 8; r = atomicAdd(&run[b], 1);
            buf[r] = (unsigned)s4.x | ((unsigned)(d4.x & 255) << 17); bkt[r] = (unsigned short)b;
            b = d4.y >> 8; r = atomicAdd(&run[b], 1);
            buf[r] = (unsigned)s4.y | ((unsigned)(d4.y & 255) << 17); bkt[r] = (unsigned short)b;
            b = d4.z >> 8; r = atomicAdd(&run[b], 1);
            buf[r] = (unsigned)s4.z | ((unsigned)(d4.z & 255) << 17); bkt[r] = (unsigned short)b;
            b = d4.w >> 8; r = atomicAdd(&run[b], 1);
            buf[r] = (unsigned)s4.w | ((unsigned)(d4.w & 255) << 17); bkt[r] = (unsigned short)b;
        } else {
            for (int q = e; q < e1; q++) {
                int d = dst[q], s = src[q], b = d >> 8;
                int r = atomicAdd(&run[b], 1);
                buf[r] = (unsigned)s | ((unsigned)(d & 255) << 17);
                bkt[r] = (unsigned short)b;
            }
        }
    }
    __syncthreads();
    // phase 4: linear coalesced copy-out
    int m = e1 - e0;
    for (int i = t; i < m; i += 256) {
        int b = bkt[i];
        pairs[gbase[b] + i - lofs[b]] = buf[i];
    }
}

// exact per-bucket counts + exclusive scan -> compact CSR bases
__global__ __launch_bounds__(256) void k_escan(const int* __restrict__ bcur,
                                               int* __restrict__ cnt,
                                               int* __restrict__ ebase, int K) {
    __shared__ int sc[KMAX], ss[256];
    int t = threadIdx.x;
    for (int i = t; i < KMAX; i += 256) sc[i] = (i < K) ? (bcur[i] - i * CAP) : 0;
    __syncthreads();
    int a0 = sc[2 * t], a1 = sc[2 * t + 1];
    int psum = a0 + a1;
    ss[t] = psum;
    for (int d = 1; d < 256; d <<= 1) {
        __syncthreads();
        int add = (t >= d) ? ss[t - d] : 0;
        __syncthreads();
        ss[t] += add;
    }
    __syncthreads();
    int excl = ss[t] - psum;
    if (2 * t < K)     { cnt[2 * t] = a0;     ebase[2 * t] = excl; }
    if (2 * t + 1 < K) { cnt[2 * t + 1] = a1; ebase[2 * t + 1] = excl + a0; }
}

// per-bucket counting sort: pairs -> compact node-ordered srcidx + off + dis
__global__ __launch_bounds__(256) void k_sort(const unsigned int* __restrict__ pairs,
                                              const int* __restrict__ ebase,
                                              const int* __restrict__ cnt,
                                              int* __restrict__ srcidx,
                                              int* __restrict__ off,
                                              float* __restrict__ dis, int n) {
    __shared__ int lcnt[NPB], pre[NPB], cur[NPB];
    int b = blockIdx.x, t = threadIdx.x;
    lcnt[t] = 0;
    __syncthreads();
    int base = b * CAP, m = cnt[b], eb = ebase[b];
    for (int j = t; j < m; j += 256) atomicAdd(&lcnt[pairs[base + j] >> 17], 1);
    __syncthreads();
    int v = lcnt[t];
    pre[t] = v;
    for (int d = 1; d < 256; d <<= 1) {
        __syncthreads();
        int add = (t >= d) ? pre[t - d] : 0;
        __syncthreads();
        pre[t] += add;
    }
    __syncthreads();
    int excl = pre[t] - v;
    cur[t] = excl;
    int node = (b << 8) + t;
    if (node < n) {
        off[node] = eb + excl;
        dis[node] = rsqrtf((float)(v + 1));
    }
    __syncthreads();
    for (int j = t; j < m; j += 256) {
        unsigned p = pairs[base + j];
        int pos = eb + atomicAdd(&cur[p >> 17], 1);
        srcidx[pos] = (int)(p & 0x1FFFF);
    }
}

// MFMA gemm1: g16[nd][c] = f16(dis[nd] * (x @ W1)[nd][c]).
__global__ __launch_bounds__(256) void k_gemm1(const float* __restrict__ x,
                                               const float* __restrict__ W1,
                                               const float* __restrict__ dis,
                                               __half* __restrict__ g16, int n) {
    int l = threadIdx.x & 63;
    int cc = l & 15, kg = l >> 4;
    f16x8 bfrag[4];
#pragma unroll
    for (int kc = 0; kc < 4; kc++)
#pragma unroll
        for (int j = 0; j < 8; j++)
            bfrag[kc][j] = (_Float16)W1[(kc * 32 + kg * 8 + j) * HDIM + cc];
    int tile = blockIdx.x * 4 + (threadIdx.x >> 6);
    int node0 = tile * 16;
    if (node0 >= n) return;
    const float* xr = x + (size_t)(node0 + cc) * FIN;
    f32x4 acc = {0.f, 0.f, 0.f, 0.f};
#pragma unroll
    for (int kc = 0; kc < 4; kc++) {
        float4 xa = *reinterpret_cast<const float4*>(xr + kc * 32 + kg * 8);
        float4 xb = *reinterpret_cast<const float4*>(xr + kc * 32 + kg * 8 + 4);
        f16x8 a;
        a[0] = (_Float16)xa.x; a[1] = (_Float16)xa.y;
        a[2] = (_Float16)xa.z; a[3] = (_Float16)xa.w;
        a[4] = (_Float16)xb.x; a[5] = (_Float16)xb.y;
        a[6] = (_Float16)xb.z; a[7] = (_Float16)xb.w;
        acc = __builtin_amdgcn_mfma_f32_16x16x32_f16(a, bfrag[kc], acc, 0, 0, 0);
    }
#pragma unroll
    for (int i = 0; i < 4; i++) {
        int nd = node0 + kg * 4 + i;
        g16[(size_t)nd * HDIM + cc] = (__half)(dis[nd] * acc[i]);
    }
}

// MFMA gemm2: g16 = f16(dis * (h @ W2)), K=16 zero-padded to 32.
__global__ __launch_bounds__(256) void k_gemm2(const float* __restrict__ h,
                                               const float* __restrict__ W2,
                                               const float* __restrict__ dis,
                                               __half* __restrict__ g16, int n) {
    int l = threadIdx.x & 63;
    int cc = l & 15, kg = l >> 4;
    f16x8 bfrag = {0, 0, 0, 0, 0, 0, 0, 0};
    if (kg < 2) {
#pragma unroll
        for (int j = 0; j < 8; j++)
            bfrag[j] = (_Float16)W2[(kg * 8 + j) * HDIM + cc];
    }
    int tile = blockIdx.x * 4 + (threadIdx.x >> 6);
    int node0 = tile * 16;
    if (node0 >= n) return;
    f16x8 a = {0, 0, 0, 0, 0, 0, 0, 0};
    if (kg < 2) {
        const float* hr = h + (size_t)(node0 + cc) * HDIM + kg * 8;
        float4 xa = *reinterpret_cast<const float4*>(hr);
        float4 xb = *reinterpret_cast<const float4*>(hr + 4);
        a[0] = (_Float16)xa.x; a[1] = (_Float16)xa.y;
        a[2] = (_Float16)xa.z; a[3] = (_Float16)xa.w;
        a[4] = (_Float16)xb.x; a[5] = (_Float16)xb.y;
        a[6] = (_Float16)xb.z; a[7] = (_Float16)xb.w;
    }
    f32x4 acc = {0.f, 0.f, 0.f, 0.f};
    acc = __builtin_amdgcn_mfma_f32_16x16x32_f16(a, bfrag, acc, 0, 0, 0);
#pragma unroll
    for (int i = 0; i < 4; i++) {
        int nd = node0 + kg * 4 + i;
        g16[(size_t)nd * HDIM + cc] = (__half)(dis[nd] * acc[i]);
    }
}

// aggregation: 4 threads per node (piece = 16B half-row, half = edge parity).
// Each thread gathers every other edge, 4-wide unrolled; halves combined via
// shfl_xor(2). h[n] = relu(dis[n] * (g16[n] + sum g16[src]) + bias)
__global__ __launch_bounds__(256) void k_agg16(const __half* __restrict__ g16,
                                               const int* __restrict__ off,
                                               const int* __restrict__ srcidx,
                                               const float* __restrict__ dis,
                                               const float* __restrict__ bias,
                                               float* __restrict__ h, int n) {
    int tid = blockIdx.x * 256 + threadIdx.x;
    int node = tid >> 2, sub = tid & 3;
    int piece = sub & 1, half = sub >> 1;
    if (node >= n) return;
    const uint4* gp = reinterpret_cast<const uint4*>(g16);
    int e0 = off[node], e1 = off[node + 1];
    __half2 a0, a1, a2, a3;
    if (half == 0) {  // self-loop term once
        uint4 v = gp[(size_t)node * 2 + piece];
        a0 = __builtin_bit_cast(__half2, v.x);
        a1 = __builtin_bit_cast(__half2, v.y);
        a2 = __builtin_bit_cast(__half2, v.z);
        a3 = __builtin_bit_cast(__half2, v.w);
    } else {
        a0 = __half2{0, 0}; a1 = __half2{0, 0};
        a2 = __half2{0, 0}; a3 = __half2{0, 0};
    }
    int e = e0 + half;
    // 4-wide unroll: 4 srcidx + 4 gathers in flight
    for (; e + 6 < e1; e += 8) {
        int s0 = srcidx[e],     s1 = srcidx[e + 2];
        int s2 = srcidx[e + 4], s3 = srcidx[e + 6];
        uint4 w0 = gp[(size_t)s0 * 2 + piece];
        uint4 w1 = gp[(size_t)s1 * 2 + piece];
        uint4 w2 = gp[(size_t)s2 * 2 + piece];
        uint4 w3 = gp[(size_t)s3 * 2 + piece];
        a0 = __hadd2(a0, __builtin_bit_cast(__half2, w0.x));
        a1 = __hadd2(a1, __builtin_bit_cast(__half2, w0.y));
        a2 = __hadd2(a2, __builtin_bit_cast(__half2, w0.z));
        a3 = __hadd2(a3, __builtin_bit_cast(__half2, w0.w));
        a0 = __hadd2(a0, __builtin_bit_cast(__half2, w1.x));
        a1 = __hadd2(a1, __builtin_bit_cast(__half2, w1.y));
        a2 = __hadd2(a2, __builtin_bit_cast(__half2, w1.z));
        a3 = __hadd2(a3, __builtin_bit_cast(__half2, w1.w));
        a0 = __hadd2(a0, __builtin_bit_cast(__half2, w2.x));
        a1 = __hadd2(a1, __builtin_bit_cast(__half2, w2.y));
        a2 = __hadd2(a2, __builtin_bit_cast(__half2, w2.z));
        a3 = __hadd2(a3, __builtin_bit_cast(__half2, w2.w));
        a0 = __hadd2(a0, __builtin_bit_cast(__half2, w3.x));
        a1 = __hadd2(a1, __builtin_bit_cast(__half2, w3.y));
        a2 = __hadd2(a2, __builtin_bit_cast(__half2, w3.z));
        a3 = __hadd2(a3, __builtin_bit_cast(__half2, w3.w));
    }
    for (; e < e1; e += 2) {
        uint4 w = gp[(size_t)srcidx[e] * 2 + piece];
        a0 = __hadd2(a0, __builtin_bit_cast(__half2, w.x));
        a1 = __hadd2(a1, __builtin_bit_cast(__half2, w.y));
        a2 = __hadd2(a2, __builtin_bit_cast(__half2, w.z));
        a3 = __hadd2(a3, __builtin_bit_cast(__half2, w.w));
    }
    // combine halves: lanes differing in bit 1 hold same piece, other parity
    a0 = __hadd2(a0, __builtin_bit_cast(__half2, __shfl_xor(__builtin_bit_cast(unsigned, a0), 2)));
    a1 = __hadd2(a1, __builtin_bit_cast(__half2, __shfl_xor(__builtin_bit_cast(unsigned, a1), 2)));
    a2 = __hadd2(a2, __builtin_bit_cast(__half2, __shfl_xor(__builtin_bit_cast(unsigned, a2), 2)));
    a3 = __hadd2(a3, __builtin_bit_cast(__half2, __shfl_xor(__builtin_bit_cast(unsigned, a3), 2)));
    if (half == 0) {
        float dn = dis[node];
        const float* bp = bias + piece * 8;
        float2 f0 = __half22float2(a0), f1 = __half22float2(a1);
        float2 f2 = __half22float2(a2), f3 = __half22float2(a3);
        float4 o0, o1;
        o0.x = fmaxf(dn * f0.x + bp[0], 0.f); o0.y = fmaxf(dn * f0.y + bp[1], 0.f);
        o0.z = fmaxf(dn * f1.x + bp[2], 0.f); o0.w = fmaxf(dn * f1.y + bp[3], 0.f);
        o1.x = fmaxf(dn * f2.x + bp[4], 0.f); o1.y = fmaxf(dn * f2.y + bp[5], 0.f);
        o1.z = fmaxf(dn * f3.x + bp[6], 0.f); o1.w = fmaxf(dn * f3.y + bp[7], 0.f);
        float4* hp = reinterpret_cast<float4*>(h + (size_t)node * HDIM + piece * 8);
        hp[0] = o0; hp[1] = o1;
    }
}

// global max pool over nodes (h >= 0 after relu, so uint atomicMax works)
__global__ __launch_bounds__(256) void k_maxpool(const float* __restrict__ h,
                                                 unsigned int* __restrict__ pooled, int n) {
    int t = threadIdx.x;
    int c = t & 15;
    int grp = t >> 4;  // 16 groups per block
    float m = 0.f;
    for (int node = blockIdx.x * 16 + grp; node < n; node += gridDim.x * 16)
        m = fmaxf(m, h[(size_t)node * HDIM + c]);
    __shared__ float s[256];
    s[t] = m;
    __syncthreads();
    for (int d = 128; d >= 16; d >>= 1) {
        if (t < d) s[t] = fmaxf(s[t], s[t + d]);
        __syncthreads();
    }
    if (t < 16) atomicMax(&pooled[t], __float_as_uint(s[t]));
}

// out[a] = sum_c pooled[c] * Wc[c][a] + bc[a]   (Wc: [16,10])
__global__ void k_final(const unsigned int* __restrict__ pooled, const float* __restrict__ Wc,
                        const float* __restrict__ bc, float* __restrict__ out) {
    __shared__ float p[HDIM];
    int t = threadIdx.x;
    if (t < HDIM) p[t] = __uint_as_float(pooled[t]);
    __syncthreads();
    if (t < AOUT) {
        float acc = bc[t];
#pragma unroll
        for (int c = 0; c < HDIM; c++) acc += p[c] * Wc[c * AOUT + t];
        out[t] = acc;
    }
}

extern "C" void kernel_launch(void* const* d_in, const int* in_sizes, int n_in,
                              void* d_out, int out_size, void* d_ws, size_t ws_size,
                              hipStream_t stream) {
    const float* x  = (const float*)d_in[0];
    const int*   ei = (const int*)d_in[1];
    const float* W1 = (const float*)d_in[2];
    const float* b1 = (const float*)d_in[3];
    const float* W2 = (const float*)d_in[4];
    const float* b2 = (const float*)d_in[5];
    const float* Wc = (const float*)d_in[6];
    const float* bc = (const float*)d_in[7];
    float* out = (float*)d_out;

    int n = in_sizes[0] / FIN;
    int E = in_sizes[1] / 2;
    const int* srcp = ei;       // edge_index[0]
    const int* dstp = ei + E;   // edge_index[1]
    int K = (n + NPB - 1) / NPB;   // 391 for n=100000

    char* ws = (char*)d_ws;
    auto alloc = [&](size_t bytes) -> char* {
        char* p = ws;
        ws += (bytes + 255) & ~(size_t)255;
        return p;
    };
    float*        dis   = (float*)alloc((size_t)n * 4);
    int*          cnt   = (int*)alloc((size_t)K * 4);
    int*          ebase = (int*)alloc((size_t)K * 4);
    int*          bcur  = (int*)alloc((size_t)K * 4);
    int*          off   = (int*)alloc((size_t)(n + 1) * 4);
    unsigned int* pairs = (unsigned int*)alloc((size_t)K * CAP * 4);
    int*          srcidx= (int*)alloc((size_t)E * 4);
    __half*       g16   = (__half*)alloc((size_t)n * HDIM * 2);
    float*        h     = (float*)alloc((size_t)n * HDIM * 4);
    unsigned int* pooled= (unsigned int*)alloc(64);

    hipMemsetAsync(pooled, 0, 64, stream);

    k_init<<<(K + 255) / 256, 256, 0, stream>>>(bcur, off, K, n, E);
    k_bin<<<(E + TILE - 1) / TILE, 256, 0, stream>>>(srcp, dstp, E, bcur, pairs, K);
    k_escan<<<1, 256, 0, stream>>>(bcur, cnt, ebase, K);
    k_sort<<<K, 256, 0, stream>>>(pairs, ebase, cnt, srcidx, off, dis, n);

    int ntile = (n + 15) / 16;
    int gblocks = (ntile + 3) / 4;
    k_gemm1<<<gblocks, 256, 0, stream>>>(x, W1, dis, g16, n);
    k_agg16<<<(4 * n + 255) / 256, 256, 0, stream>>>(g16, off, srcidx, dis, b1, h, n);
    k_gemm2<<<gblocks, 256, 0, stream>>>(h, W2, dis, g16, n);
    k_agg16<<<(4 * n + 255) / 256, 256, 0, stream>>>(g16, off, srcidx, dis, b2, h, n);

    k_maxpool<<<256, 256, 0, stream>>>(h, pooled, n);
    k_final<<<1, 64, 0, stream>>>(pooled, Wc, bc, out);
}

// Round 9
// 145.394 us; speedup vs baseline: 1.8487x; 1.0585x over previous
//
#include <hip/hip_runtime.h>
#include <hip/hip_fp16.h>

// GCN policy net: 2× GCNConv(H=16) + global max pool + linear head.
// Build: fixed-capacity coarse buckets -> k_bin tile-local LDS reorder ->
// k_sort (512 thr, padded per-bucket node-ordered srcidx + off2 + dis).
// Compute: MFMA f16 gemms; messages g16 = [n][16] fp16 (3.2MB, L2-resident).
// Aggregate: 4 threads/node (piece x parity), 8-wide unrolled gather loop.
// No hipMemsetAsync in the timed path (pooled zeroed in k_init: the runtime
// fillBuffer dispatch measured ~40us in the captured graph).

#define FIN 128
#define HDIM 16
#define AOUT 10
#define NPB 256      // nodes per bucket (bucket = dst >> 8)
#define KMAX 512     // LDS sizing bound (padded): supports n <= 131072
#define TILE 4096    // edges per k_bin tile
#define CAP 9216     // fixed bucket capacity (expected 8192, sigma~90)

typedef _Float16 f16x8 __attribute__((ext_vector_type(8)));
typedef float f32x4 __attribute__((ext_vector_type(4)));

// init bucket cursors to arithmetic bases; zero pooled
__global__ void k_init(int* __restrict__ bcur, unsigned int* __restrict__ pooled,
                       int K) {
    int i = blockIdx.x * 256 + threadIdx.x;
    if (i < K) bcur[i] = i * CAP;
    if (i < 16) pooled[i] = 0u;
}

// tile-local reorder: histogram -> LDS scan -> bucket-sorted LDS buffer ->
// linear coalesced copy-out to per-bucket global windows.
__global__ __launch_bounds__(256) void k_bin(const int* __restrict__ src,
                                             const int* __restrict__ dst, int E,
                                             int* __restrict__ bcur,
                                             unsigned int* __restrict__ pairs, int K) {
    __shared__ int hist[KMAX], lofs[KMAX], run[KMAX], gbase[KMAX], ss[256];
    __shared__ unsigned int buf[TILE];
    __shared__ unsigned short bkt[TILE];
    int t = threadIdx.x;
    int e0 = blockIdx.x * TILE;
    int e1 = min(E, e0 + TILE);
    for (int i = t; i < KMAX; i += 256) hist[i] = 0;
    __syncthreads();
    // phase 1: tile histogram
    for (int e = e0 + t * 4; e < e1; e += 1024) {
        if (e + 4 <= e1) {
            int4 d4 = *reinterpret_cast<const int4*>(dst + e);
            atomicAdd(&hist[d4.x >> 8], 1);
            atomicAdd(&hist[d4.y >> 8], 1);
            atomicAdd(&hist[d4.z >> 8], 1);
            atomicAdd(&hist[d4.w >> 8], 1);
        } else {
            for (int q = e; q < e1; q++) atomicAdd(&hist[dst[q] >> 8], 1);
        }
    }
    __syncthreads();
    // phase 2: exclusive scan over padded 512 (2 entries per thread)
    int a0 = hist[2 * t], a1 = hist[2 * t + 1];
    int psum = a0 + a1;
    ss[t] = psum;
    for (int d = 1; d < 256; d <<= 1) {
        __syncthreads();
        int add = (t >= d) ? ss[t - d] : 0;
        __syncthreads();
        ss[t] += add;
    }
    __syncthreads();
    int excl = ss[t] - psum;
    lofs[2 * t] = excl;          run[2 * t] = excl;
    lofs[2 * t + 1] = excl + a0; run[2 * t + 1] = excl + a0;
    __syncthreads();
    // reserve global windows (one atomic per non-empty bucket)
    for (int b = t; b < K; b += 256)
        if (hist[b]) gbase[b] = atomicAdd(&bcur[b], hist[b]);
    __syncthreads();
    // phase 3: scatter into bucket-sorted LDS buffer
    for (int e = e0 + t * 4; e < e1; e += 1024) {
        if (e + 4 <= e1) {
            int4 d4 = *reinterpret_cast<const int4*>(dst + e);
            int4 s4 = *reinterpret_cast<const int4*>(src + e);
            int b, r;
            b = d4.x >> 8; r = atomicAdd(&run[b], 1);
            buf[r] = (unsigned)s4.x | ((unsigned)(d4.x & 255) << 17); bkt[r] = (unsigned short)b;
            b = d4.y >> 8; r = atomicAdd(&run[b], 1);
            buf[r] = (unsigned)s4.y | ((unsigned)(d4.y & 255) << 17); bkt[r] = (unsigned short)b;
            b = d4.z >> 8; r = atomicAdd(&run[b], 1);
            buf[r] = (unsigned)s4.z | ((unsigned)(d4.z & 255) << 17); bkt[r] = (unsigned short)b;
            b = d4.w >> 8; r = atomicAdd(&run[b], 1);
            buf[r] = (unsigned)s4.w | ((unsigned)(d4.w & 255) << 17); bkt[r] = (unsigned short)b;
        } else {
            for (int q = e; q < e1; q++) {
                int d = dst[q], s = src[q], b = d >> 8;
                int r = atomicAdd(&run[b], 1);
                buf[r] = (unsigned)s | ((unsigned)(d & 255) << 17);
                bkt[r] = (unsigned short)b;
            }
        }
    }
    __syncthreads();
    // phase 4: linear coalesced copy-out
    int m = e1 - e0;
    for (int i = t; i < m; i += 256) {
        int b = bkt[i];
        pairs[gbase[b] + i - lofs[b]] = buf[i];
    }
}

// per-bucket counting sort: pairs -> node-ordered srcidx (padded layout,
// bases b*CAP) + off2 (start,end) + dis. Counts read from bcur.
__global__ __launch_bounds__(512) void k_sort(const unsigned int* __restrict__ pairs,
                                              const int* __restrict__ bcur,
                                              int* __restrict__ srcidx,
                                              int2* __restrict__ off2,
                                              float* __restrict__ dis, int n) {
    __shared__ int lcnt[NPB], pre[NPB], cur[NPB];
    int b = blockIdx.x, t = threadIdx.x;
    if (t < NPB) lcnt[t] = 0;
    __syncthreads();
    int base = b * CAP;
    int m = bcur[b] - base;
    for (int j = t; j < m; j += 512) atomicAdd(&lcnt[pairs[base + j] >> 17], 1);
    __syncthreads();
    int v = (t < NPB) ? lcnt[t] : 0;
    if (t < NPB) pre[t] = v;
    for (int d = 1; d < NPB; d <<= 1) {
        __syncthreads();
        int add = (t < NPB && t >= d) ? pre[t - d] : 0;
        __syncthreads();
        if (t < NPB) pre[t] += add;
    }
    __syncthreads();
    if (t < NPB) {
        int excl = pre[t] - v;
        cur[t] = excl;
        int node = (b << 8) + t;
        if (node < n) {
            off2[node] = make_int2(base + excl, base + excl + v);
            dis[node] = rsqrtf((float)(v + 1));
        }
    }
    __syncthreads();
    for (int j = t; j < m; j += 512) {
        unsigned p = pairs[base + j];
        int pos = base + atomicAdd(&cur[p >> 17], 1);
        srcidx[pos] = (int)(p & 0x1FFFF);
    }
}

// MFMA gemm1: g16[nd][c] = f16(dis[nd] * (x @ W1)[nd][c]).
__global__ __launch_bounds__(256) void k_gemm1(const float* __restrict__ x,
                                               const float* __restrict__ W1,
                                               const float* __restrict__ dis,
                                               __half* __restrict__ g16, int n) {
    int l = threadIdx.x & 63;
    int cc = l & 15, kg = l >> 4;
    f16x8 bfrag[4];
#pragma unroll
    for (int kc = 0; kc < 4; kc++)
#pragma unroll
        for (int j = 0; j < 8; j++)
            bfrag[kc][j] = (_Float16)W1[(kc * 32 + kg * 8 + j) * HDIM + cc];
    int tile = blockIdx.x * 4 + (threadIdx.x >> 6);
    int node0 = tile * 16;
    if (node0 >= n) return;
    const float* xr = x + (size_t)(node0 + cc) * FIN;
    f32x4 acc = {0.f, 0.f, 0.f, 0.f};
#pragma unroll
    for (int kc = 0; kc < 4; kc++) {
        float4 xa = *reinterpret_cast<const float4*>(xr + kc * 32 + kg * 8);
        float4 xb = *reinterpret_cast<const float4*>(xr + kc * 32 + kg * 8 + 4);
        f16x8 a;
        a[0] = (_Float16)xa.x; a[1] = (_Float16)xa.y;
        a[2] = (_Float16)xa.z; a[3] = (_Float16)xa.w;
        a[4] = (_Float16)xb.x; a[5] = (_Float16)xb.y;
        a[6] = (_Float16)xb.z; a[7] = (_Float16)xb.w;
        acc = __builtin_amdgcn_mfma_f32_16x16x32_f16(a, bfrag[kc], acc, 0, 0, 0);
    }
#pragma unroll
    for (int i = 0; i < 4; i++) {
        int nd = node0 + kg * 4 + i;
        g16[(size_t)nd * HDIM + cc] = (__half)(dis[nd] * acc[i]);
    }
}

// MFMA gemm2: g16 = f16(dis * (h @ W2)), K=16 zero-padded to 32.
__global__ __launch_bounds__(256) void k_gemm2(const float* __restrict__ h,
                                               const float* __restrict__ W2,
                                               const float* __restrict__ dis,
                                               __half* __restrict__ g16, int n) {
    int l = threadIdx.x & 63;
    int cc = l & 15, kg = l >> 4;
    f16x8 bfrag = {0, 0, 0, 0, 0, 0, 0, 0};
    if (kg < 2) {
#pragma unroll
        for (int j = 0; j < 8; j++)
            bfrag[j] = (_Float16)W2[(kg * 8 + j) * HDIM + cc];
    }
    int tile = blockIdx.x * 4 + (threadIdx.x >> 6);
    int node0 = tile * 16;
    if (node0 >= n) return;
    f16x8 a = {0, 0, 0, 0, 0, 0, 0, 0};
    if (kg < 2) {
        const float* hr = h + (size_t)(node0 + cc) * HDIM + kg * 8;
        float4 xa = *reinterpret_cast<const float4*>(hr);
        float4 xb = *reinterpret_cast<const float4*>(hr + 4);
        a[0] = (_Float16)xa.x; a[1] = (_Float16)xa.y;
        a[2] = (_Float16)xa.z; a[3] = (_Float16)xa.w;
        a[4] = (_Float16)xb.x; a[5] = (_Float16)xb.y;
        a[6] = (_Float16)xb.z; a[7] = (_Float16)xb.w;
    }
    f32x4 acc = {0.f, 0.f, 0.f, 0.f};
    acc = __builtin_amdgcn_mfma_f32_16x16x32_f16(a, bfrag, acc, 0, 0, 0);
#pragma unroll
    for (int i = 0; i < 4; i++) {
        int nd = node0 + kg * 4 + i;
        g16[(size_t)nd * HDIM + cc] = (__half)(dis[nd] * acc[i]);
    }
}

// aggregation: 4 threads/node (piece = 16B half-row, half = edge parity).
// 8-wide unrolled gather loop (8 independent 16B gathers in flight/thread);
// halves combined via shfl_xor(2). h[n] = relu(dis*(g16[n]+sum g16[src])+b)
__global__ __launch_bounds__(256) void k_agg16(const __half* __restrict__ g16,
                                               const int2* __restrict__ off2,
                                               const int* __restrict__ srcidx,
                                               const float* __restrict__ dis,
                                               const float* __restrict__ bias,
                                               float* __restrict__ h, int n) {
    int tid = blockIdx.x * 256 + threadIdx.x;
    int node = tid >> 2, sub = tid & 3;
    int piece = sub & 1, half = sub >> 1;
    if (node >= n) return;
    const uint4* gp = reinterpret_cast<const uint4*>(g16);
    int2 oe = off2[node];
    int e0 = oe.x, e1 = oe.y;
    __half2 a0, a1, a2, a3;
    if (half == 0) {  // self-loop term once
        uint4 v = gp[(size_t)node * 2 + piece];
        a0 = __builtin_bit_cast(__half2, v.x);
        a1 = __builtin_bit_cast(__half2, v.y);
        a2 = __builtin_bit_cast(__half2, v.z);
        a3 = __builtin_bit_cast(__half2, v.w);
    } else {
        a0 = __half2{0, 0}; a1 = __half2{0, 0};
        a2 = __half2{0, 0}; a3 = __half2{0, 0};
    }
    int e = e0 + half;
    // 8-wide unroll: 8 srcidx + 8 gathers in flight
    for (; e + 14 < e1; e += 16) {
        int s0 = srcidx[e];      int s1 = srcidx[e + 2];
        int s2 = srcidx[e + 4];  int s3 = srcidx[e + 6];
        int s4 = srcidx[e + 8];  int s5 = srcidx[e + 10];
        int s6 = srcidx[e + 12]; int s7 = srcidx[e + 14];
        uint4 w0 = gp[(size_t)s0 * 2 + piece];
        uint4 w1 = gp[(size_t)s1 * 2 + piece];
        uint4 w2 = gp[(size_t)s2 * 2 + piece];
        uint4 w3 = gp[(size_t)s3 * 2 + piece];
        uint4 w4 = gp[(size_t)s4 * 2 + piece];
        uint4 w5 = gp[(size_t)s5 * 2 + piece];
        uint4 w6 = gp[(size_t)s6 * 2 + piece];
        uint4 w7 = gp[(size_t)s7 * 2 + piece];
        a0 = __hadd2(a0, __builtin_bit_cast(__half2, w0.x));
        a1 = __hadd2(a1, __builtin_bit_cast(__half2, w0.y));
        a2 = __hadd2(a2, __builtin_bit_cast(__half2, w0.z));
        a3 = __hadd2(a3, __builtin_bit_cast(__half2, w0.w));
        a0 = __hadd2(a0, __builtin_bit_cast(__half2, w1.x));
        a1 = __hadd2(a1, __builtin_bit_cast(__half2, w1.y));
        a2 = __hadd2(a2, __builtin_bit_cast(__half2, w1.z));
        a3 = __hadd2(a3, __builtin_bit_cast(__half2, w1.w));
        a0 = __hadd2(a0, __builtin_bit_cast(__half2, w2.x));
        a1 = __hadd2(a1, __builtin_bit_cast(__half2, w2.y));
        a2 = __hadd2(a2, __builtin_bit_cast(__half2, w2.z));
        a3 = __hadd2(a3, __builtin_bit_cast(__half2, w2.w));
        a0 = __hadd2(a0, __builtin_bit_cast(__half2, w3.x));
        a1 = __hadd2(a1, __builtin_bit_cast(__half2, w3.y));
        a2 = __hadd2(a2, __builtin_bit_cast(__half2, w3.z));
        a3 = __hadd2(a3, __builtin_bit_cast(__half2, w3.w));
        a0 = __hadd2(a0, __builtin_bit_cast(__half2, w4.x));
        a1 = __hadd2(a1, __builtin_bit_cast(__half2, w4.y));
        a2 = __hadd2(a2, __builtin_bit_cast(__half2, w4.z));
        a3 = __hadd2(a3, __builtin_bit_cast(__half2, w4.w));
        a0 = __hadd2(a0, __builtin_bit_cast(__half2, w5.x));
        a1 = __hadd2(a1, __builtin_bit_cast(__half2, w5.y));
        a2 = __hadd2(a2, __builtin_bit_cast(__half2, w5.z));
        a3 = __hadd2(a3, __builtin_bit_cast(__half2, w5.w));
        a0 = __hadd2(a0, __builtin_bit_cast(__half2, w6.x));
        a1 = __hadd2(a1, __builtin_bit_cast(__half2, w6.y));
        a2 = __hadd2(a2, __builtin_bit_cast(__half2, w6.z));
        a3 = __hadd2(a3, __builtin_bit_cast(__half2, w6.w));
        a0 = __hadd2(a0, __builtin_bit_cast(__half2, w7.x));
        a1 = __hadd2(a1, __builtin_bit_cast(__half2, w7.y));
        a2 = __hadd2(a2, __builtin_bit_cast(__half2, w7.z));
        a3 = __hadd2(a3, __builtin_bit_cast(__half2, w7.w));
    }
    for (; e < e1; e += 2) {
        uint4 w = gp[(size_t)srcidx[e] * 2 + piece];
        a0 = __hadd2(a0, __builtin_bit_cast(__half2, w.x));
        a1 = __hadd2(a1, __builtin_bit_cast(__half2, w.y));
        a2 = __hadd2(a2, __builtin_bit_cast(__half2, w.z));
        a3 = __hadd2(a3, __builtin_bit_cast(__half2, w.w));
    }
    // combine halves: lanes differing in bit 1 hold same piece, other parity
    a0 = __hadd2(a0, __builtin_bit_cast(__half2, __shfl_xor(__builtin_bit_cast(unsigned, a0), 2)));
    a1 = __hadd2(a1, __builtin_bit_cast(__half2, __shfl_xor(__builtin_bit_cast(unsigned, a1), 2)));
    a2 = __hadd2(a2, __builtin_bit_cast(__half2, __shfl_xor(__builtin_bit_cast(unsigned, a2), 2)));
    a3 = __hadd2(a3, __builtin_bit_cast(__half2, __shfl_xor(__builtin_bit_cast(unsigned, a3), 2)));
    if (half == 0) {
        float dn = dis[node];
        const float* bp = bias + piece * 8;
        float2 f0 = __half22float2(a0), f1 = __half22float2(a1);
        float2 f2 = __half22float2(a2), f3 = __half22float2(a3);
        float4 o0, o1;
        o0.x = fmaxf(dn * f0.x + bp[0], 0.f); o0.y = fmaxf(dn * f0.y + bp[1], 0.f);
        o0.z = fmaxf(dn * f1.x + bp[2], 0.f); o0.w = fmaxf(dn * f1.y + bp[3], 0.f);
        o1.x = fmaxf(dn * f2.x + bp[4], 0.f); o1.y = fmaxf(dn * f2.y + bp[5], 0.f);
        o1.z = fmaxf(dn * f3.x + bp[6], 0.f); o1.w = fmaxf(dn * f3.y + bp[7], 0.f);
        float4* hp = reinterpret_cast<float4*>(h + (size_t)node * HDIM + piece * 8);
        hp[0] = o0; hp[1] = o1;
    }
}

// global max pool over nodes (h >= 0 after relu, so uint atomicMax works)
__global__ __launch_bounds__(256) void k_maxpool(const float* __restrict__ h,
                                                 unsigned int* __restrict__ pooled, int n) {
    int t = threadIdx.x;
    int c = t & 15;
    int grp = t >> 4;  // 16 groups per block
    float m = 0.f;
    for (int node = blockIdx.x * 16 + grp; node < n; node += gridDim.x * 16)
        m = fmaxf(m, h[(size_t)node * HDIM + c]);
    __shared__ float s[256];
    s[t] = m;
    __syncthreads();
    for (int d = 128; d >= 16; d >>= 1) {
        if (t < d) s[t] = fmaxf(s[t], s[t + d]);
        __syncthreads();
    }
    if (t < 16) atomicMax(&pooled[t], __float_as_uint(s[t]));
}

// out[a] = sum_c pooled[c] * Wc[c][a] + bc[a]   (Wc: [16,10])
__global__ void k_final(const unsigned int* __restrict__ pooled, const float* __restrict__ Wc,
                        const float* __restrict__ bc, float* __restrict__ out) {
    __shared__ float p[HDIM];
    int t = threadIdx.x;
    if (t < HDIM) p[t] = __uint_as_float(pooled[t]);
    __syncthreads();
    if (t < AOUT) {
        float acc = bc[t];
#pragma unroll
        for (int c = 0; c < HDIM; c++) acc += p[c] * Wc[c * AOUT + t];
        out[t] = acc;
    }
}

extern "C" void kernel_launch(void* const* d_in, const int* in_sizes, int n_in,
                              void* d_out, int out_size, void* d_ws, size_t ws_size,
                              hipStream_t stream) {
    const float* x  = (const float*)d_in[0];
    const int*   ei = (const int*)d_in[1];
    const float* W1 = (const float*)d_in[2];
    const float* b1 = (const float*)d_in[3];
    const float* W2 = (const float*)d_in[4];
    const float* b2 = (const float*)d_in[5];
    const float* Wc = (const float*)d_in[6];
    const float* bc = (const float*)d_in[7];
    float* out = (float*)d_out;

    int n = in_sizes[0] / FIN;
    int E = in_sizes[1] / 2;
    const int* srcp = ei;       // edge_index[0]
    const int* dstp = ei + E;   // edge_index[1]
    int K = (n + NPB - 1) / NPB;   // 391 for n=100000

    char* ws = (char*)d_ws;
    auto alloc = [&](size_t bytes) -> char* {
        char* p = ws;
        ws += (bytes + 255) & ~(size_t)255;
        return p;
    };
    float*        dis   = (float*)alloc((size_t)n * 4);
    int*          bcur  = (int*)alloc((size_t)K * 4);
    int2*         off2  = (int2*)alloc((size_t)n * 8);
    unsigned int* pairs = (unsigned int*)alloc((size_t)K * CAP * 4);
    int*          srcidx= (int*)alloc((size_t)K * CAP * 4);
    __half*       g16   = (__half*)alloc((size_t)n * HDIM * 2);
    float*        h     = (float*)alloc((size_t)n * HDIM * 4);
    unsigned int* pooled= (unsigned int*)alloc(64);

    k_init<<<(K + 255) / 256, 256, 0, stream>>>(bcur, pooled, K);
    k_bin<<<(E + TILE - 1) / TILE, 256, 0, stream>>>(srcp, dstp, E, bcur, pairs, K);
    k_sort<<<K, 512, 0, stream>>>(pairs, bcur, srcidx, off2, dis, n);

    int ntile = (n + 15) / 16;
    int gblocks = (ntile + 3) / 4;
    k_gemm1<<<gblocks, 256, 0, stream>>>(x, W1, dis, g16, n);
    k_agg16<<<(4 * n + 255) / 256, 256, 0, stream>>>(g16, off2, srcidx, dis, b1, h, n);
    k_gemm2<<<gblocks, 256, 0, stream>>>(h, W2, dis, g16, n);
    k_agg16<<<(4 * n + 255) / 256, 256, 0, stream>>>(g16, off2, srcidx, dis, b2, h, n);

    k_maxpool<<<256, 256, 0, stream>>>(h, pooled, n);
    k_final<<<1, 64, 0, stream>>>(pooled, Wc, bc, out);
}

// Round 11
// 137.686 us; speedup vs baseline: 1.9522x; 1.0560x over previous
//
#include <hip/hip_runtime.h>
#include <hip/hip_fp16.h>

// GCN policy net: 2× GCNConv(H=16) + global max pool + linear head.
// Build: fixed-capacity coarse buckets -> k_bin tile-local LDS reorder ->
// k_sort (node-ordered srcidx, 4-ALIGNED per-node segments padded with
// sentinel index n -> zero g16 row; off2 + dis).
// Compute: MFMA f16 gemms; messages g16 = [n+1][16] fp16 (row n = 0).
// Aggregate: 4 threads/node (piece x 4-edge-chunk parity), int4 srcidx
// loads (1 index lane-address per 4 edges), 8 gathers in flight; layer 2
// fuses global max pool in the epilogue (h never hits HBM).

#define FIN 128
#define HDIM 16
#define AOUT 10
#define NPB 256      // nodes per bucket (bucket = dst >> 8)
#define KMAX 512     // LDS sizing bound (padded): supports n <= 131072
#define TILE 4096    // edges per k_bin tile
#define CAP 10240    // bucket capacity (max count ~8560 + align pad <=768)

typedef _Float16 f16x8 __attribute__((ext_vector_type(8)));
typedef float f32x4 __attribute__((ext_vector_type(4)));

// init bucket cursors; zero pooled; zero sentinel row g16[n]
__global__ void k_init(int* __restrict__ bcur, unsigned int* __restrict__ pooled,
                       unsigned int* __restrict__ gz, int K) {
    int i = blockIdx.x * 256 + threadIdx.x;
    if (i < K) bcur[i] = i * CAP;
    if (i < 16) pooled[i] = 0u;
    if (i < 8) gz[i] = 0u;   // 32B zero row at g16 + n*16
}

// tile-local reorder: histogram -> LDS scan -> bucket-sorted LDS buffer ->
// linear coalesced copy-out to per-bucket global windows.
__global__ __launch_bounds__(256) void k_bin(const int* __restrict__ src,
                                             const int* __restrict__ dst, int E,
                                             int* __restrict__ bcur,
                                             unsigned int* __restrict__ pairs, int K) {
    __shared__ int hist[KMAX], lofs[KMAX], run[KMAX], gbase[KMAX], ss[256];
    __shared__ unsigned int buf[TILE];
    __shared__ unsigned short bkt[TILE];
    int t = threadIdx.x;
    int e0 = blockIdx.x * TILE;
    int e1 = min(E, e0 + TILE);
    for (int i = t; i < KMAX; i += 256) hist[i] = 0;
    __syncthreads();
    // phase 1: tile histogram
    for (int e = e0 + t * 4; e < e1; e += 1024) {
        if (e + 4 <= e1) {
            int4 d4 = *reinterpret_cast<const int4*>(dst + e);
            atomicAdd(&hist[d4.x >> 8], 1);
            atomicAdd(&hist[d4.y >> 8], 1);
            atomicAdd(&hist[d4.z >> 8], 1);
            atomicAdd(&hist[d4.w >> 8], 1);
        } else {
            for (int q = e; q < e1; q++) atomicAdd(&hist[dst[q] >> 8], 1);
        }
    }
    __syncthreads();
    // phase 2: exclusive scan over padded 512 (2 entries per thread)
    int a0 = hist[2 * t], a1 = hist[2 * t + 1];
    int psum = a0 + a1;
    ss[t] = psum;
    for (int d = 1; d < 256; d <<= 1) {
        __syncthreads();
        int add = (t >= d) ? ss[t - d] : 0;
        __syncthreads();
        ss[t] += add;
    }
    __syncthreads();
    int excl = ss[t] - psum;
    lofs[2 * t] = excl;          run[2 * t] = excl;
    lofs[2 * t + 1] = excl + a0; run[2 * t + 1] = excl + a0;
    __syncthreads();
    // reserve global windows (one atomic per non-empty bucket)
    for (int b = t; b < K; b += 256)
        if (hist[b]) gbase[b] = atomicAdd(&bcur[b], hist[b]);
    __syncthreads();
    // phase 3: scatter into bucket-sorted LDS buffer
    for (int e = e0 + t * 4; e < e1; e += 1024) {
        if (e + 4 <= e1) {
            int4 d4 = *reinterpret_cast<const int4*>(dst + e);
            int4 s4 = *reinterpret_cast<const int4*>(src + e);
            int b, r;
            b = d4.x >> 8; r = atomicAdd(&run[b], 1);
            buf[r] = (unsigned)s4.x | ((unsigned)(d4.x & 255) << 17); bkt[r] = (unsigned short)b;
            b = d4.y >> 8; r = atomicAdd(&run[b], 1);
            buf[r] = (unsigned)s4.y | ((unsigned)(d4.y & 255) << 17); bkt[r] = (unsigned short)b;
            b = d4.z >> 8; r = atomicAdd(&run[b], 1);
            buf[r] = (unsigned)s4.z | ((unsigned)(d4.z & 255) << 17); bkt[r] = (unsigned short)b;
            b = d4.w >> 8; r = atomicAdd(&run[b], 1);
            buf[r] = (unsigned)s4.w | ((unsigned)(d4.w & 255) << 17); bkt[r] = (unsigned short)b;
        } else {
            for (int q = e; q < e1; q++) {
                int d = dst[q], s = src[q], b = d >> 8;
                int r = atomicAdd(&run[b], 1);
                buf[r] = (unsigned)s | ((unsigned)(d & 255) << 17);
                bkt[r] = (unsigned short)b;
            }
        }
    }
    __syncthreads();
    // phase 4: linear coalesced copy-out
    int m = e1 - e0;
    for (int i = t; i < m; i += 256) {
        int b = bkt[i];
        pairs[gbase[b] + i - lofs[b]] = buf[i];
    }
}

// per-bucket counting sort: pairs -> node-ordered srcidx with 4-aligned
// segment starts (pad slots = n, the zero row) + off2 (start,end) + dis.
__global__ __launch_bounds__(512) void k_sort(const unsigned int* __restrict__ pairs,
                                              const int* __restrict__ bcur,
                                              int* __restrict__ srcidx,
                                              int2* __restrict__ off2,
                                              float* __restrict__ dis, int n) {
    __shared__ int lcnt[NPB], pre[NPB], cur[NPB];
    int b = blockIdx.x, t = threadIdx.x;
    if (t < NPB) lcnt[t] = 0;
    __syncthreads();
    int base = b * CAP;
    int m = bcur[b] - base;
    for (int j = t; j < m; j += 512) atomicAdd(&lcnt[pairs[base + j] >> 17], 1);
    __syncthreads();
    int v = (t < NPB) ? lcnt[t] : 0;
    int w = (v + 3) & ~3;               // 4-aligned segment size
    if (t < NPB) pre[t] = w;
    for (int d = 1; d < NPB; d <<= 1) {
        __syncthreads();
        int add = (t < NPB && t >= d) ? pre[t - d] : 0;
        __syncthreads();
        if (t < NPB) pre[t] += add;
    }
    __syncthreads();
    if (t < NPB) {
        int start = pre[t] - w;
        cur[t] = start;
        int node = (b << 8) + t;
        if (node < n) {
            off2[node] = make_int2(base + start, base + start + v);
            dis[node] = rsqrtf((float)(v + 1));
        }
        for (int p = v; p < w; p++) srcidx[base + start + p] = n;  // sentinel
    }
    __syncthreads();
    for (int j = t; j < m; j += 512) {
        unsigned p = pairs[base + j];
        int pos = base + atomicAdd(&cur[p >> 17], 1);
        srcidx[pos] = (int)(p & 0x1FFFF);
    }
}

// MFMA gemm1: g16[nd][c] = f16(dis[nd] * (x @ W1)[nd][c]).
__global__ __launch_bounds__(256) void k_gemm1(const float* __restrict__ x,
                                               const float* __restrict__ W1,
                                               const float* __restrict__ dis,
                                               __half* __restrict__ g16, int n) {
    int l = threadIdx.x & 63;
    int cc = l & 15, kg = l >> 4;
    f16x8 bfrag[4];
#pragma unroll
    for (int kc = 0; kc < 4; kc++)
#pragma unroll
        for (int j = 0; j < 8; j++)
            bfrag[kc][j] = (_Float16)W1[(kc * 32 + kg * 8 + j) * HDIM + cc];
    int tile = blockIdx.x * 4 + (threadIdx.x >> 6);
    int node0 = tile * 16;
    if (node0 >= n) return;
    const float* xr = x + (size_t)(node0 + cc) * FIN;
    f32x4 acc = {0.f, 0.f, 0.f, 0.f};
#pragma unroll
    for (int kc = 0; kc < 4; kc++) {
        float4 xa = *reinterpret_cast<const float4*>(xr + kc * 32 + kg * 8);
        float4 xb = *reinterpret_cast<const float4*>(xr + kc * 32 + kg * 8 + 4);
        f16x8 a;
        a[0] = (_Float16)xa.x; a[1] = (_Float16)xa.y;
        a[2] = (_Float16)xa.z; a[3] = (_Float16)xa.w;
        a[4] = (_Float16)xb.x; a[5] = (_Float16)xb.y;
        a[6] = (_Float16)xb.z; a[7] = (_Float16)xb.w;
        acc = __builtin_amdgcn_mfma_f32_16x16x32_f16(a, bfrag[kc], acc, 0, 0, 0);
    }
#pragma unroll
    for (int i = 0; i < 4; i++) {
        int nd = node0 + kg * 4 + i;
        g16[(size_t)nd * HDIM + cc] = (__half)(dis[nd] * acc[i]);
    }
}

// MFMA gemm2: g16 = f16(dis * (h @ W2)), K=16 zero-padded to 32.
__global__ __launch_bounds__(256) void k_gemm2(const float* __restrict__ h,
                                               const float* __restrict__ W2,
                                               const float* __restrict__ dis,
                                               __half* __restrict__ g16, int n) {
    int l = threadIdx.x & 63;
    int cc = l & 15, kg = l >> 4;
    f16x8 bfrag = {0, 0, 0, 0, 0, 0, 0, 0};
    if (kg < 2) {
#pragma unroll
        for (int j = 0; j < 8; j++)
            bfrag[j] = (_Float16)W2[(kg * 8 + j) * HDIM + cc];
    }
    int tile = blockIdx.x * 4 + (threadIdx.x >> 6);
    int node0 = tile * 16;
    if (node0 >= n) return;
    f16x8 a = {0, 0, 0, 0, 0, 0, 0, 0};
    if (kg < 2) {
        const float* hr = h + (size_t)(node0 + cc) * HDIM + kg * 8;
        float4 xa = *reinterpret_cast<const float4*>(hr);
        float4 xb = *reinterpret_cast<const float4*>(hr + 4);
        a[0] = (_Float16)xa.x; a[1] = (_Float16)xa.y;
        a[2] = (_Float16)xa.z; a[3] = (_Float16)xa.w;
        a[4] = (_Float16)xb.x; a[5] = (_Float16)xb.y;
        a[6] = (_Float16)xb.z; a[7] = (_Float16)xb.w;
    }
    f32x4 acc = {0.f, 0.f, 0.f, 0.f};
    acc = __builtin_amdgcn_mfma_f32_16x16x32_f16(a, bfrag, acc, 0, 0, 0);
#pragma unroll
    for (int i = 0; i < 4; i++) {
        int nd = node0 + kg * 4 + i;
        g16[(size_t)nd * HDIM + cc] = (__half)(dis[nd] * acc[i]);
    }
}

#define ACC4(V) \
    a0 = __hadd2(a0, __builtin_bit_cast(__half2, (V).x)); \
    a1 = __hadd2(a1, __builtin_bit_cast(__half2, (V).y)); \
    a2 = __hadd2(a2, __builtin_bit_cast(__half2, (V).z)); \
    a3 = __hadd2(a3, __builtin_bit_cast(__half2, (V).w));

// aggregation: 4 threads/node (piece = 16B half-row, half = 4-edge-chunk
// parity). int4 srcidx loads, 8 gathers in flight. POOL=1 fuses global max
// pool (h never written). h[n] = relu(dis*(g16[n]+sum g16[src])+bias)
template <int POOL>
__global__ __launch_bounds__(256) void k_agg16(const __half* __restrict__ g16,
                                               const int2* __restrict__ off2,
                                               const int* __restrict__ srcidx,
                                               const float* __restrict__ dis,
                                               const float* __restrict__ bias,
                                               float* __restrict__ h,
                                               unsigned int* __restrict__ pooled,
                                               int n) {
    __shared__ float smax[4][16];
    int t = threadIdx.x;
    int tid = blockIdx.x * 256 + t;
    int node = tid >> 2, sub = t & 3;
    int piece = sub & 1, half = sub >> 1;
    bool active = node < n;
    float4 o0 = {0.f, 0.f, 0.f, 0.f}, o1 = {0.f, 0.f, 0.f, 0.f};
    if (active) {
        const uint4* gp = reinterpret_cast<const uint4*>(g16);
        int2 oe = off2[node];
        int e0 = oe.x, e1 = oe.y;
        __half2 a0{0, 0}, a1{0, 0}, a2{0, 0}, a3{0, 0};
        if (half == 0) {  // self-loop term once
            uint4 v = gp[(size_t)node * 2 + piece];
            ACC4(v)
        }
        int e = e0 + 4 * half;
        for (; e + 8 < e1; e += 16) {  // 2 chunks: 2 int4 + 8 gathers in flight
            int4 sa = *reinterpret_cast<const int4*>(srcidx + e);
            int4 sb = *reinterpret_cast<const int4*>(srcidx + e + 8);
            uint4 w0 = gp[(size_t)sa.x * 2 + piece];
            uint4 w1 = gp[(size_t)sa.y * 2 + piece];
            uint4 w2 = gp[(size_t)sa.z * 2 + piece];
            uint4 w3 = gp[(size_t)sa.w * 2 + piece];
            uint4 w4 = gp[(size_t)sb.x * 2 + piece];
            uint4 w5 = gp[(size_t)sb.y * 2 + piece];
            uint4 w6 = gp[(size_t)sb.z * 2 + piece];
            uint4 w7 = gp[(size_t)sb.w * 2 + piece];
            ACC4(w0) ACC4(w1) ACC4(w2) ACC4(w3)
            ACC4(w4) ACC4(w5) ACC4(w6) ACC4(w7)
        }
        for (; e < e1; e += 8) {  // tail chunk (pads gather zero row)
            int4 sa = *reinterpret_cast<const int4*>(srcidx + e);
            uint4 w0 = gp[(size_t)sa.x * 2 + piece];
            uint4 w1 = gp[(size_t)sa.y * 2 + piece];
            uint4 w2 = gp[(size_t)sa.z * 2 + piece];
            uint4 w3 = gp[(size_t)sa.w * 2 + piece];
            ACC4(w0) ACC4(w1) ACC4(w2) ACC4(w3)
        }
        // combine chunk-parity halves (lanes differ in bit 1)
        a0 = __hadd2(a0, __builtin_bit_cast(__half2, __shfl_xor(__builtin_bit_cast(unsigned, a0), 2)));
        a1 = __hadd2(a1, __builtin_bit_cast(__half2, __shfl_xor(__builtin_bit_cast(unsigned, a1), 2)));
        a2 = __hadd2(a2, __builtin_bit_cast(__half2, __shfl_xor(__builtin_bit_cast(unsigned, a2), 2)));
        a3 = __hadd2(a3, __builtin_bit_cast(__half2, __shfl_xor(__builtin_bit_cast(unsigned, a3), 2)));
        if (half == 0) {
            float dn = dis[node];
            const float* bp = bias + piece * 8;
            float2 f0 = __half22float2(a0), f1 = __half22float2(a1);
            float2 f2 = __half22float2(a2), f3 = __half22float2(a3);
            o0.x = fmaxf(dn * f0.x + bp[0], 0.f); o0.y = fmaxf(dn * f0.y + bp[1], 0.f);
            o0.z = fmaxf(dn * f1.x + bp[2], 0.f); o0.w = fmaxf(dn * f1.y + bp[3], 0.f);
            o1.x = fmaxf(dn * f2.x + bp[4], 0.f); o1.y = fmaxf(dn * f2.y + bp[5], 0.f);
            o1.z = fmaxf(dn * f3.x + bp[6], 0.f); o1.w = fmaxf(dn * f3.y + bp[7], 0.f);
            if (!POOL) {
                float4* hp = reinterpret_cast<float4*>(h + (size_t)node * HDIM + piece * 8);
                hp[0] = o0; hp[1] = o1;
            }
        }
    }
    if (POOL) {
        // wave-reduce over nodes (xor >= 4 preserves sub class); h >= 0
#pragma unroll
        for (int d = 4; d <= 32; d <<= 1) {
            o0.x = fmaxf(o0.x, __shfl_xor(o0.x, d)); o0.y = fmaxf(o0.y, __shfl_xor(o0.y, d));
            o0.z = fmaxf(o0.z, __shfl_xor(o0.z, d)); o0.w = fmaxf(o0.w, __shfl_xor(o0.w, d));
            o1.x = fmaxf(o1.x, __shfl_xor(o1.x, d)); o1.y = fmaxf(o1.y, __shfl_xor(o1.y, d));
            o1.z = fmaxf(o1.z, __shfl_xor(o1.z, d)); o1.w = fmaxf(o1.w, __shfl_xor(o1.w, d));
        }
        int wv = t >> 6;
        if ((t & 63) < 2) {  // lane 0: piece0, lane 1: piece1 (half==0 class)
            float* sp = &smax[wv][piece * 8];
            sp[0] = o0.x; sp[1] = o0.y; sp[2] = o0.z; sp[3] = o0.w;
            sp[4] = o1.x; sp[5] = o1.y; sp[6] = o1.z; sp[7] = o1.w;
        }
        __syncthreads();
        if (t < 16) {
            float m = fmaxf(fmaxf(smax[0][t], smax[1][t]), fmaxf(smax[2][t], smax[3][t]));
            atomicMax(&pooled[t], __float_as_uint(m));
        }
    }
}

// out[a] = sum_c pooled[c] * Wc[c][a] + bc[a]   (Wc: [16,10])
__global__ void k_final(const unsigned int* __restrict__ pooled, const float* __restrict__ Wc,
                        const float* __restrict__ bc, float* __restrict__ out) {
    __shared__ float p[HDIM];
    int t = threadIdx.x;
    if (t < HDIM) p[t] = __uint_as_float(pooled[t]);
    __syncthreads();
    if (t < AOUT) {
        float acc = bc[t];
#pragma unroll
        for (int c = 0; c < HDIM; c++) acc += p[c] * Wc[c * AOUT + t];
        out[t] = acc;
    }
}

extern "C" void kernel_launch(void* const* d_in, const int* in_sizes, int n_in,
                              void* d_out, int out_size, void* d_ws, size_t ws_size,
                              hipStream_t stream) {
    const float* x  = (const float*)d_in[0];
    const int*   ei = (const int*)d_in[1];
    const float* W1 = (const float*)d_in[2];
    const float* b1 = (const float*)d_in[3];
    const float* W2 = (const float*)d_in[4];
    const float* b2 = (const float*)d_in[5];
    const float* Wc = (const float*)d_in[6];
    const float* bc = (const float*)d_in[7];
    float* out = (float*)d_out;

    int n = in_sizes[0] / FIN;
    int E = in_sizes[1] / 2;
    const int* srcp = ei;       // edge_index[0]
    const int* dstp = ei + E;   // edge_index[1]
    int K = (n + NPB - 1) / NPB;   // 391 for n=100000

    char* ws = (char*)d_ws;
    auto alloc = [&](size_t bytes) -> char* {
        char* p = ws;
        ws += (bytes + 255) & ~(size_t)255;
        return p;
    };
    float*        dis   = (float*)alloc((size_t)n * 4);
    int*          bcur  = (int*)alloc((size_t)K * 4);
    int2*         off2  = (int2*)alloc((size_t)n * 8);
    unsigned int* pairs = (unsigned int*)alloc((size_t)K * CAP * 4);
    int*          srcidx= (int*)alloc((size_t)K * CAP * 4);
    __half*       g16   = (__half*)alloc((size_t)(n + 1) * HDIM * 2);
    float*        h     = (float*)alloc((size_t)n * HDIM * 4);
    unsigned int* pooled= (unsigned int*)alloc(64);

    k_init<<<(K + 255) / 256, 256, 0, stream>>>(bcur, pooled,
                                                (unsigned int*)(g16 + (size_t)n * HDIM), K);
    k_bin<<<(E + TILE - 1) / TILE, 256, 0, stream>>>(srcp, dstp, E, bcur, pairs, K);
    k_sort<<<K, 512, 0, stream>>>(pairs, bcur, srcidx, off2, dis, n);

    int ntile = (n + 15) / 16;
    int gblocks = (ntile + 3) / 4;
    k_gemm1<<<gblocks, 256, 0, stream>>>(x, W1, dis, g16, n);
    k_agg16<0><<<(4 * n + 255) / 256, 256, 0, stream>>>(g16, off2, srcidx, dis, b1,
                                                        h, pooled, n);
    k_gemm2<<<gblocks, 256, 0, stream>>>(h, W2, dis, g16, n);
    k_agg16<1><<<(4 * n + 255) / 256, 256, 0, stream>>>(g16, off2, srcidx, dis, b2,
                                                        nullptr, pooled, n);

    k_final<<<1, 64, 0, stream>>>(pooled, Wc, bc, out);
}

// Round 12
// 131.408 us; speedup vs baseline: 2.0454x; 1.0478x over previous
//
#include <hip/hip_runtime.h>
#include <hip/hip_fp16.h>

// GCN policy net: 2× GCNConv(H=16) + global max pool + linear head.
// Build: fixed-capacity coarse buckets -> k_bin tile-local LDS reorder ->
// k_sort (register-staged single pairs read; node-ordered srcidx with
// 4-aligned segments, sentinel pad -> zero g16 row; off2 + dis).
// Compute: MFMA f16 gemm1; layer-1 agg fuses the 16x16 W2 matmul in its
// epilogue (4 sub-lanes = j-half x c-half quadrants, W2 in LDS) -> g16b;
// layer-2 agg fuses global max pool. h never exists; gemm2 kernel deleted.

#define FIN 128
#define HDIM 16
#define AOUT 10
#define NPB 256      // nodes per bucket (bucket = dst >> 8)
#define KMAX 512     // LDS sizing bound (padded): supports n <= 131072
#define TILE 4096    // edges per k_bin tile
#define CAP 10240    // bucket capacity (max count ~8560 + align pad <=768)

typedef _Float16 f16x8 __attribute__((ext_vector_type(8)));
typedef float f32x4 __attribute__((ext_vector_type(4)));

// init bucket cursors; zero pooled; zero sentinel rows of both g16 buffers
__global__ void k_init(int* __restrict__ bcur, unsigned int* __restrict__ pooled,
                       unsigned int* __restrict__ gza, unsigned int* __restrict__ gzb,
                       int K) {
    int i = blockIdx.x * 256 + threadIdx.x;
    if (i < K) bcur[i] = i * CAP;
    if (i < 16) pooled[i] = 0u;
    if (i < 8) { gza[i] = 0u; gzb[i] = 0u; }   // 32B zero rows
}

// tile-local reorder: histogram -> LDS scan -> bucket-sorted LDS buffer ->
// linear coalesced copy-out to per-bucket global windows.
__global__ __launch_bounds__(256) void k_bin(const int* __restrict__ src,
                                             const int* __restrict__ dst, int E,
                                             int* __restrict__ bcur,
                                             unsigned int* __restrict__ pairs, int K) {
    __shared__ int hist[KMAX], lofs[KMAX], run[KMAX], gbase[KMAX], ss[256];
    __shared__ unsigned int buf[TILE];
    __shared__ unsigned short bkt[TILE];
    int t = threadIdx.x;
    int e0 = blockIdx.x * TILE;
    int e1 = min(E, e0 + TILE);
    for (int i = t; i < KMAX; i += 256) hist[i] = 0;
    __syncthreads();
    // phase 1: tile histogram
    for (int e = e0 + t * 4; e < e1; e += 1024) {
        if (e + 4 <= e1) {
            int4 d4 = *reinterpret_cast<const int4*>(dst + e);
            atomicAdd(&hist[d4.x >> 8], 1);
            atomicAdd(&hist[d4.y >> 8], 1);
            atomicAdd(&hist[d4.z >> 8], 1);
            atomicAdd(&hist[d4.w >> 8], 1);
        } else {
            for (int q = e; q < e1; q++) atomicAdd(&hist[dst[q] >> 8], 1);
        }
    }
    __syncthreads();
    // phase 2: exclusive scan over padded 512 (2 entries per thread)
    int a0 = hist[2 * t], a1 = hist[2 * t + 1];
    int psum = a0 + a1;
    ss[t] = psum;
    for (int d = 1; d < 256; d <<= 1) {
        __syncthreads();
        int add = (t >= d) ? ss[t - d] : 0;
        __syncthreads();
        ss[t] += add;
    }
    __syncthreads();
    int excl = ss[t] - psum;
    lofs[2 * t] = excl;          run[2 * t] = excl;
    lofs[2 * t + 1] = excl + a0; run[2 * t + 1] = excl + a0;
    __syncthreads();
    // reserve global windows (one atomic per non-empty bucket)
    for (int b = t; b < K; b += 256)
        if (hist[b]) gbase[b] = atomicAdd(&bcur[b], hist[b]);
    __syncthreads();
    // phase 3: scatter into bucket-sorted LDS buffer
    for (int e = e0 + t * 4; e < e1; e += 1024) {
        if (e + 4 <= e1) {
            int4 d4 = *reinterpret_cast<const int4*>(dst + e);
            int4 s4 = *reinterpret_cast<const int4*>(src + e);
            int b, r;
            b = d4.x >> 8; r = atomicAdd(&run[b], 1);
            buf[r] = (unsigned)s4.x | ((unsigned)(d4.x & 255) << 17); bkt[r] = (unsigned short)b;
            b = d4.y >> 8; r = atomicAdd(&run[b], 1);
            buf[r] = (unsigned)s4.y | ((unsigned)(d4.y & 255) << 17); bkt[r] = (unsigned short)b;
            b = d4.z >> 8; r = atomicAdd(&run[b], 1);
            buf[r] = (unsigned)s4.z | ((unsigned)(d4.z & 255) << 17); bkt[r] = (unsigned short)b;
            b = d4.w >> 8; r = atomicAdd(&run[b], 1);
            buf[r] = (unsigned)s4.w | ((unsigned)(d4.w & 255) << 17); bkt[r] = (unsigned short)b;
        } else {
            for (int q = e; q < e1; q++) {
                int d = dst[q], s = src[q], b = d >> 8;
                int r = atomicAdd(&run[b], 1);
                buf[r] = (unsigned)s | ((unsigned)(d & 255) << 17);
                bkt[r] = (unsigned short)b;
            }
        }
    }
    __syncthreads();
    // phase 4: linear coalesced copy-out
    int m = e1 - e0;
    for (int i = t; i < m; i += 256) {
        int b = bkt[i];
        pairs[gbase[b] + i - lofs[b]] = buf[i];
    }
}

// per-bucket counting sort (register-staged: single pairs read) ->
// node-ordered srcidx with 4-aligned segments (pads = n) + off2 + dis.
__global__ __launch_bounds__(512) void k_sort(const unsigned int* __restrict__ pairs,
                                              const int* __restrict__ bcur,
                                              int* __restrict__ srcidx,
                                              int2* __restrict__ off2,
                                              float* __restrict__ dis, int n) {
    __shared__ int lcnt[NPB], pre[NPB], cur[NPB];
    int b = blockIdx.x, t = threadIdx.x;
    if (t < NPB) lcnt[t] = 0;
    __syncthreads();
    int base = b * CAP;
    int m = bcur[b] - base;
    unsigned loc[20];   // fixed unroll -> static indices (no scratch)
#pragma unroll
    for (int q = 0; q < 20; q++) {
        int j = t + q * 512;
        loc[q] = (j < m) ? pairs[base + j] : 0u;
        if (j < m) atomicAdd(&lcnt[loc[q] >> 17], 1);
    }
    __syncthreads();
    int v = (t < NPB) ? lcnt[t] : 0;
    int w = (v + 3) & ~3;               // 4-aligned segment size
    if (t < NPB) pre[t] = w;
    for (int d = 1; d < NPB; d <<= 1) {
        __syncthreads();
        int add = (t < NPB && t >= d) ? pre[t - d] : 0;
        __syncthreads();
        if (t < NPB) pre[t] += add;
    }
    __syncthreads();
    if (t < NPB) {
        int start = pre[t] - w;
        cur[t] = start;
        int node = (b << 8) + t;
        if (node < n) {
            off2[node] = make_int2(base + start, base + start + v);
            dis[node] = rsqrtf((float)(v + 1));
        }
        for (int p = v; p < w; p++) srcidx[base + start + p] = n;  // sentinel
    }
    __syncthreads();
#pragma unroll
    for (int q = 0; q < 20; q++) {
        int j = t + q * 512;
        if (j < m) {
            unsigned p = loc[q];
            int pos = base + atomicAdd(&cur[p >> 17], 1);
            srcidx[pos] = (int)(p & 0x1FFFF);
        }
    }
}

// MFMA gemm1: g16[nd][c] = f16(dis[nd] * (x @ W1)[nd][c]).
__global__ __launch_bounds__(256) void k_gemm1(const float* __restrict__ x,
                                               const float* __restrict__ W1,
                                               const float* __restrict__ dis,
                                               __half* __restrict__ g16, int n) {
    int l = threadIdx.x & 63;
    int cc = l & 15, kg = l >> 4;
    f16x8 bfrag[4];
#pragma unroll
    for (int kc = 0; kc < 4; kc++)
#pragma unroll
        for (int j = 0; j < 8; j++)
            bfrag[kc][j] = (_Float16)W1[(kc * 32 + kg * 8 + j) * HDIM + cc];
    int tile = blockIdx.x * 4 + (threadIdx.x >> 6);
    int node0 = tile * 16;
    if (node0 >= n) return;
    const float* xr = x + (size_t)(node0 + cc) * FIN;
    f32x4 acc = {0.f, 0.f, 0.f, 0.f};
#pragma unroll
    for (int kc = 0; kc < 4; kc++) {
        float4 xa = *reinterpret_cast<const float4*>(xr + kc * 32 + kg * 8);
        float4 xb = *reinterpret_cast<const float4*>(xr + kc * 32 + kg * 8 + 4);
        f16x8 a;
        a[0] = (_Float16)xa.x; a[1] = (_Float16)xa.y;
        a[2] = (_Float16)xa.z; a[3] = (_Float16)xa.w;
        a[4] = (_Float16)xb.x; a[5] = (_Float16)xb.y;
        a[6] = (_Float16)xb.z; a[7] = (_Float16)xb.w;
        acc = __builtin_amdgcn_mfma_f32_16x16x32_f16(a, bfrag[kc], acc, 0, 0, 0);
    }
#pragma unroll
    for (int i = 0; i < 4; i++) {
        int nd = node0 + kg * 4 + i;
        g16[(size_t)nd * HDIM + cc] = (__half)(dis[nd] * acc[i]);
    }
}

#define ACC4(V) \
    a0 = __hadd2(a0, __builtin_bit_cast(__half2, (V).x)); \
    a1 = __hadd2(a1, __builtin_bit_cast(__half2, (V).y)); \
    a2 = __hadd2(a2, __builtin_bit_cast(__half2, (V).z)); \
    a3 = __hadd2(a3, __builtin_bit_cast(__half2, (V).w));

#define GATHER_LOOP \
    int e = e0 + 4 * half; \
    for (; e + 8 < e1; e += 16) { \
        int4 sa = *reinterpret_cast<const int4*>(srcidx + e); \
        int4 sb = *reinterpret_cast<const int4*>(srcidx + e + 8); \
        uint4 w0 = gp[(size_t)sa.x * 2 + piece]; \
        uint4 w1 = gp[(size_t)sa.y * 2 + piece]; \
        uint4 w2 = gp[(size_t)sa.z * 2 + piece]; \
        uint4 w3 = gp[(size_t)sa.w * 2 + piece]; \
        uint4 w4 = gp[(size_t)sb.x * 2 + piece]; \
        uint4 w5 = gp[(size_t)sb.y * 2 + piece]; \
        uint4 w6 = gp[(size_t)sb.z * 2 + piece]; \
        uint4 w7 = gp[(size_t)sb.w * 2 + piece]; \
        ACC4(w0) ACC4(w1) ACC4(w2) ACC4(w3) \
        ACC4(w4) ACC4(w5) ACC4(w6) ACC4(w7) \
    } \
    for (; e < e1; e += 8) { \
        int4 sa = *reinterpret_cast<const int4*>(srcidx + e); \
        uint4 w0 = gp[(size_t)sa.x * 2 + piece]; \
        uint4 w1 = gp[(size_t)sa.y * 2 + piece]; \
        uint4 w2 = gp[(size_t)sa.z * 2 + piece]; \
        uint4 w3 = gp[(size_t)sa.w * 2 + piece]; \
        ACC4(w0) ACC4(w1) ACC4(w2) ACC4(w3) \
    } \
    a0 = __hadd2(a0, __builtin_bit_cast(__half2, __shfl_xor(__builtin_bit_cast(unsigned, a0), 2))); \
    a1 = __hadd2(a1, __builtin_bit_cast(__half2, __shfl_xor(__builtin_bit_cast(unsigned, a1), 2))); \
    a2 = __hadd2(a2, __builtin_bit_cast(__half2, __shfl_xor(__builtin_bit_cast(unsigned, a2), 2))); \
    a3 = __hadd2(a3, __builtin_bit_cast(__half2, __shfl_xor(__builtin_bit_cast(unsigned, a3), 2)));

// layer-1 aggregation + fused W2 matmul. 4 threads/node (piece x chunk
// parity); after combine all 4 sub-lanes hold the full sums -> each computes
// its relu'd h half, then the (j-half x c-half) quadrant of h@W2 from LDS W2,
// combined via shfl_xor(1); dis-scaled, f16-packed -> g16out.
__global__ __launch_bounds__(256) void k_agg_g2(const __half* __restrict__ g16in,
                                                const int2* __restrict__ off2,
                                                const int* __restrict__ srcidx,
                                                const float* __restrict__ dis,
                                                const float* __restrict__ bias,
                                                const float* __restrict__ W2,
                                                __half* __restrict__ g16out, int n) {
    __shared__ float W2s[HDIM * HDIM];
    int t = threadIdx.x;
    W2s[t] = W2[t];     // blockDim == 256 == HDIM*HDIM
    __syncthreads();
    int tid = blockIdx.x * 256 + t;
    int node = tid >> 2, sub = t & 3;
    int piece = sub & 1, half = sub >> 1;
    if (node >= n) return;
    const uint4* gp = reinterpret_cast<const uint4*>(g16in);
    int2 oe = off2[node];
    int e0 = oe.x, e1 = oe.y;
    __half2 a0{0, 0}, a1{0, 0}, a2{0, 0}, a3{0, 0};
    if (half == 0) {  // self-loop term once
        uint4 v = gp[(size_t)node * 2 + piece];
        ACC4(v)
    }
    GATHER_LOOP
    // all lanes: relu'd h for channels piece*8 .. piece*8+7
    float dn = dis[node];
    const float* bp = bias + piece * 8;
    float2 f0 = __half22float2(a0), f1 = __half22float2(a1);
    float2 f2 = __half22float2(a2), f3 = __half22float2(a3);
    float hreg[8];
    hreg[0] = fmaxf(dn * f0.x + bp[0], 0.f); hreg[1] = fmaxf(dn * f0.y + bp[1], 0.f);
    hreg[2] = fmaxf(dn * f1.x + bp[2], 0.f); hreg[3] = fmaxf(dn * f1.y + bp[3], 0.f);
    hreg[4] = fmaxf(dn * f2.x + bp[4], 0.f); hreg[5] = fmaxf(dn * f2.y + bp[5], 0.f);
    hreg[6] = fmaxf(dn * f3.x + bp[6], 0.f); hreg[7] = fmaxf(dn * f3.y + bp[7], 0.f);
    // quadrant of h @ W2: j-range = piece*8.., c-range = half*8..
    float acc[8];
    const float* wq = W2s + (piece * 8) * HDIM + half * 8;
#pragma unroll
    for (int cc = 0; cc < 8; cc++) {
        float s = 0.f;
#pragma unroll
        for (int jj = 0; jj < 8; jj++) s += hreg[jj] * wq[jj * HDIM + cc];
        acc[cc] = s;
    }
    // combine j-halves across piece (bit 0)
#pragma unroll
    for (int cc = 0; cc < 8; cc++) acc[cc] += __shfl_xor(acc[cc], 1);
    if (piece == 0) {   // sub0 writes c 0-7, sub2 writes c 8-15
        __half o[8];
#pragma unroll
        for (int cc = 0; cc < 8; cc++) o[cc] = (__half)(dn * acc[cc]);
        *reinterpret_cast<uint4*>(g16out + (size_t)node * HDIM + half * 8) =
            *reinterpret_cast<uint4*>(o);
    }
}

// layer-2 aggregation + fused global max pool (h never written).
__global__ __launch_bounds__(256) void k_agg_pool(const __half* __restrict__ g16in,
                                                  const int2* __restrict__ off2,
                                                  const int* __restrict__ srcidx,
                                                  const float* __restrict__ dis,
                                                  const float* __restrict__ bias,
                                                  unsigned int* __restrict__ pooled,
                                                  int n) {
    __shared__ float smax[4][16];
    int t = threadIdx.x;
    int tid = blockIdx.x * 256 + t;
    int node = tid >> 2, sub = t & 3;
    int piece = sub & 1, half = sub >> 1;
    bool active = node < n;
    float4 o0 = {0.f, 0.f, 0.f, 0.f}, o1 = {0.f, 0.f, 0.f, 0.f};
    if (active) {
        const uint4* gp = reinterpret_cast<const uint4*>(g16in);
        int2 oe = off2[node];
        int e0 = oe.x, e1 = oe.y;
        __half2 a0{0, 0}, a1{0, 0}, a2{0, 0}, a3{0, 0};
        if (half == 0) {  // self-loop term once
            uint4 v = gp[(size_t)node * 2 + piece];
            ACC4(v)
        }
        GATHER_LOOP
        if (half == 0) {
            float dn = dis[node];
            const float* bp = bias + piece * 8;
            float2 f0 = __half22float2(a0), f1 = __half22float2(a1);
            float2 f2 = __half22float2(a2), f3 = __half22float2(a3);
            o0.x = fmaxf(dn * f0.x + bp[0], 0.f); o0.y = fmaxf(dn * f0.y + bp[1], 0.f);
            o0.z = fmaxf(dn * f1.x + bp[2], 0.f); o0.w = fmaxf(dn * f1.y + bp[3], 0.f);
            o1.x = fmaxf(dn * f2.x + bp[4], 0.f); o1.y = fmaxf(dn * f2.y + bp[5], 0.f);
            o1.z = fmaxf(dn * f3.x + bp[6], 0.f); o1.w = fmaxf(dn * f3.y + bp[7], 0.f);
        }
    }
    // wave-reduce over nodes (xor >= 4 preserves sub class); h >= 0
#pragma unroll
    for (int d = 4; d <= 32; d <<= 1) {
        o0.x = fmaxf(o0.x, __shfl_xor(o0.x, d)); o0.y = fmaxf(o0.y, __shfl_xor(o0.y, d));
        o0.z = fmaxf(o0.z, __shfl_xor(o0.z, d)); o0.w = fmaxf(o0.w, __shfl_xor(o0.w, d));
        o1.x = fmaxf(o1.x, __shfl_xor(o1.x, d)); o1.y = fmaxf(o1.y, __shfl_xor(o1.y, d));
        o1.z = fmaxf(o1.z, __shfl_xor(o1.z, d)); o1.w = fmaxf(o1.w, __shfl_xor(o1.w, d));
    }
    int wv = t >> 6;
    if ((t & 63) < 2) {  // lane 0: piece0, lane 1: piece1 (half==0 class)
        float* sp = &smax[wv][piece * 8];
        sp[0] = o0.x; sp[1] = o0.y; sp[2] = o0.z; sp[3] = o0.w;
        sp[4] = o1.x; sp[5] = o1.y; sp[6] = o1.z; sp[7] = o1.w;
    }
    __syncthreads();
    if (t < 16) {
        float m = fmaxf(fmaxf(smax[0][t], smax[1][t]), fmaxf(smax[2][t], smax[3][t]));
        atomicMax(&pooled[t], __float_as_uint(m));
    }
}

// out[a] = sum_c pooled[c] * Wc[c][a] + bc[a]   (Wc: [16,10])
__global__ void k_final(const unsigned int* __restrict__ pooled, const float* __restrict__ Wc,
                        const float* __restrict__ bc, float* __restrict__ out) {
    __shared__ float p[HDIM];
    int t = threadIdx.x;
    if (t < HDIM) p[t] = __uint_as_float(pooled[t]);
    __syncthreads();
    if (t < AOUT) {
        float acc = bc[t];
#pragma unroll
        for (int c = 0; c < HDIM; c++) acc += p[c] * Wc[c * AOUT + t];
        out[t] = acc;
    }
}

extern "C" void kernel_launch(void* const* d_in, const int* in_sizes, int n_in,
                              void* d_out, int out_size, void* d_ws, size_t ws_size,
                              hipStream_t stream) {
    const float* x  = (const float*)d_in[0];
    const int*   ei = (const int*)d_in[1];
    const float* W1 = (const float*)d_in[2];
    const float* b1 = (const float*)d_in[3];
    const float* W2 = (const float*)d_in[4];
    const float* b2 = (const float*)d_in[5];
    const float* Wc = (const float*)d_in[6];
    const float* bc = (const float*)d_in[7];
    float* out = (float*)d_out;

    int n = in_sizes[0] / FIN;
    int E = in_sizes[1] / 2;
    const int* srcp = ei;       // edge_index[0]
    const int* dstp = ei + E;   // edge_index[1]
    int K = (n + NPB - 1) / NPB;   // 391 for n=100000

    char* ws = (char*)d_ws;
    auto alloc = [&](size_t bytes) -> char* {
        char* p = ws;
        ws += (bytes + 255) & ~(size_t)255;
        return p;
    };
    float*        dis   = (float*)alloc((size_t)n * 4);
    int*          bcur  = (int*)alloc((size_t)K * 4);
    int2*         off2  = (int2*)alloc((size_t)n * 8);
    unsigned int* pairs = (unsigned int*)alloc((size_t)K * CAP * 4);
    int*          srcidx= (int*)alloc((size_t)K * CAP * 4);
    __half*       g16a  = (__half*)alloc((size_t)(n + 1) * HDIM * 2);
    __half*       g16b  = (__half*)alloc((size_t)(n + 1) * HDIM * 2);
    unsigned int* pooled= (unsigned int*)alloc(64);

    k_init<<<(K + 255) / 256, 256, 0, stream>>>(
        bcur, pooled,
        (unsigned int*)(g16a + (size_t)n * HDIM),
        (unsigned int*)(g16b + (size_t)n * HDIM), K);
    k_bin<<<(E + TILE - 1) / TILE, 256, 0, stream>>>(srcp, dstp, E, bcur, pairs, K);
    k_sort<<<K, 512, 0, stream>>>(pairs, bcur, srcidx, off2, dis, n);

    int ntile = (n + 15) / 16;
    int gblocks = (ntile + 3) / 4;
    k_gemm1<<<gblocks, 256, 0, stream>>>(x, W1, dis, g16a, n);
    k_agg_g2<<<(4 * n + 255) / 256, 256, 0, stream>>>(g16a, off2, srcidx, dis, b1,
                                                      W2, g16b, n);
    k_agg_pool<<<(4 * n + 255) / 256, 256, 0, stream>>>(g16b, off2, srcidx, dis, b2,
                                                        pooled, n);

    k_final<<<1, 64, 0, stream>>>(pooled, Wc, bc, out);
}